// Round 1
// baseline (365.479 us; speedup 1.0000x reference)
//
#include <hip/hip_runtime.h>
#include <math.h>

#define D   1024
#define H   16
#define HD  64
#define SEQ 2048
#define LL  8
#define SCALE 0.125f

typedef __attribute__((ext_vector_type(8))) __bf16 bf16x8;
typedef __attribute__((ext_vector_type(4))) float floatx4;
typedef __attribute__((ext_vector_type(8))) unsigned short ushort8;

__device__ inline unsigned short f32_to_bf16(float f) {
    unsigned int u = __builtin_bit_cast(unsigned int, f);
    u += 0x7FFF + ((u >> 16) & 1);   // round-to-nearest-even
    return (unsigned short)(u >> 16);
}
__device__ inline float bf2f(unsigned short u) {
    unsigned int x = (unsigned int)u << 16;
    return __builtin_bit_cast(float, x);
}
__device__ inline void load_lds16(const void* g, void* l) {
    __builtin_amdgcn_global_load_lds(
        (__attribute__((address_space(1))) void*)g,
        (__attribute__((address_space(3))) void*)l, 16, 0, 0);
}

// XCD-aware swizzle: contiguous grid chunk per XCD -> A-panel L2 reuse.
__device__ inline void xcd_swizzle(int& bx, int& by) {
    const int gx   = gridDim.x;
    const int lin  = blockIdx.y * gx + blockIdx.x;
    const int nblk = gx * gridDim.y;
    const int virt = (lin & 7) * (nblk >> 3) + (lin >> 3);
    bx = virt % gx;
    by = virt / gx;
}

// ---------------------------------------------------------------------------
// prep: LN(reproject(pv)) -> ri_bf  |  f32->bf16 of x, Wqkv|Wcol (->W4), Wout
//       |  bias concat b4 = [bqkv, bcol]
// ---------------------------------------------------------------------------
#define NQ_X    524288
#define NQ_WQKV 786432
#define NQ_WC   262144
#define NQ_WO   262144
#define LN_BLK  16384
#define CVT_BLK 7168          // (NQ_X+NQ_WQKV+NQ_WC+NQ_WO)/256
#define PREP_GRID (LN_BLK + CVT_BLK + 4)

__global__ __launch_bounds__(256) void prep_kernel(
    const float* __restrict__ pv, const float* __restrict__ x,
    const float* __restrict__ Wqkv, const float* __restrict__ Wcol,
    const float* __restrict__ Wout, const float* __restrict__ bqkv,
    const float* __restrict__ bcol,
    unsigned short* __restrict__ ri, unsigned short* __restrict__ xb,
    unsigned short* __restrict__ W4b, unsigned short* __restrict__ Woutb,
    float* __restrict__ b4)
{
    const int b = blockIdx.x;
    const int t = threadIdx.x;
    if (b < LN_BLK) {
        // LayerNorm row r = s*L + l over d=1024
        const int r = b;
        const int s = r >> 3, l = r & 7;
        const int h = t >> 4, e = (t & 15) * 4;
        const size_t src = (size_t)l * (H * SEQ * HD) + (size_t)h * (SEQ * HD)
                         + (size_t)s * HD + e;
        float4 v = *(const float4*)(pv + src);
        float sum = v.x + v.y + v.z + v.w;
        float sq  = v.x * v.x + v.y * v.y + v.z * v.z + v.w * v.w;
#pragma unroll
        for (int off = 32; off; off >>= 1) {
            sum += __shfl_xor(sum, off);
            sq  += __shfl_xor(sq, off);
        }
        __shared__ float red[8];
        if ((t & 63) == 0) { red[(t >> 6) * 2] = sum; red[(t >> 6) * 2 + 1] = sq; }
        __syncthreads();
        sum = red[0] + red[2] + red[4] + red[6];
        sq  = red[1] + red[3] + red[5] + red[7];
        const float mean = sum * (1.f / 1024.f);
        const float var  = sq * (1.f / 1024.f) - mean * mean;
        const float rstd = rsqrtf(var + 1e-5f);
        ushort4 o;
        o.x = f32_to_bf16((v.x - mean) * rstd);
        o.y = f32_to_bf16((v.y - mean) * rstd);
        o.z = f32_to_bf16((v.z - mean) * rstd);
        o.w = f32_to_bf16((v.w - mean) * rstd);
        *(ushort4*)(ri + (size_t)r * D + t * 4) = o;
    } else if (b < LN_BLK + CVT_BLK) {
        const int i = (b - LN_BLK) * 256 + t;
        const float* src; unsigned short* dst; int off;
        if (i < NQ_X)                        { src = x;    dst = xb;    off = i; }
        else if (i < NQ_X + NQ_WQKV)         { src = Wqkv; dst = W4b;   off = i - NQ_X; }
        else if (i < NQ_X + NQ_WQKV + NQ_WC) {
            float4 v = ((const float4*)Wcol)[i - NQ_X - NQ_WQKV];
            ushort4 o;
            o.x = f32_to_bf16(v.x); o.y = f32_to_bf16(v.y);
            o.z = f32_to_bf16(v.z); o.w = f32_to_bf16(v.w);
            ((ushort4*)(W4b))[NQ_WQKV + (i - NQ_X - NQ_WQKV)] = o;
            return;
        }
        else                                 { src = Wout; dst = Woutb; off = i - NQ_X - NQ_WQKV - NQ_WC; }
        float4 v = ((const float4*)src)[off];
        ushort4 o;
        o.x = f32_to_bf16(v.x); o.y = f32_to_bf16(v.y);
        o.z = f32_to_bf16(v.z); o.w = f32_to_bf16(v.w);
        ((ushort4*)dst)[off] = o;
    } else {
        // bias concat: 1024 float4 quads, first 768 from bqkv, rest from bcol
        const int q = (b - LN_BLK - CVT_BLK) * 256 + t;
        float4 v = (q < 768) ? ((const float4*)bqkv)[q] : ((const float4*)bcol)[q - 768];
        ((float4*)b4)[q] = v;
    }
}

// ---------------------------------------------------------------------------
// wkt: WkT[h][c][e] = Wqkv[1024 + h*64 + e][c]  (bf16). Grid 256 = 16h x 16ct.
// ---------------------------------------------------------------------------
__global__ __launch_bounds__(256) void wkt_kernel(
    const float* __restrict__ Wqkv, unsigned short* __restrict__ WkT)
{
    const int h = blockIdx.x >> 4, ct = blockIdx.x & 15;
    const int c0 = ct * 64;
    const int t = threadIdx.x;
    __shared__ float tile[64][68];
    {
        const int e  = t >> 2;            // 0..63
        const int c4 = (t & 3) * 16;      // 0,16,32,48
        const float* src = Wqkv + (size_t)(D + h * HD + e) * D + c0 + c4;
#pragma unroll
        for (int j = 0; j < 4; j++) {
            float4 v = ((const float4*)src)[j];
            *(float4*)&tile[e][c4 + j * 4] = v;
        }
    }
    __syncthreads();
    {
        const int c  = t >> 2;            // local col 0..63
        const int e0 = (t & 3) * 16;      // 0,16,32,48
        ushort8 o0, o1;
#pragma unroll
        for (int j = 0; j < 8; j++) o0[j] = f32_to_bf16(tile[e0 + j][c]);
#pragma unroll
        for (int j = 0; j < 8; j++) o1[j] = f32_to_bf16(tile[e0 + 8 + j][c]);
        unsigned short* dst = WkT + (size_t)h * (D * HD) + (size_t)(c0 + c) * HD + e0;
        *(ushort8*)dst       = o0;
        *(ushort8*)(dst + 8) = o1;
    }
}

// ---------------------------------------------------------------------------
// bf16 MFMA GEMM: C[M,N] = A[M,K] @ W[N,K]^T (+ bias[N]). CT = float or ushort.
// 128x128 tile, BK=32, 4 waves, 4x4 16x16x32 MFMAs per wave. XCD-swizzled.
// Generalized: lda/ldw/ldc row strides, blockIdx.z batching via element strides.
// ---------------------------------------------------------------------------
template <typename CT, bool HAS_BIAS>
__global__ __launch_bounds__(256) void gemm_bf16_kernel(
    const unsigned short* __restrict__ A, const unsigned short* __restrict__ W,
    const float* __restrict__ bias, CT* __restrict__ C,
    int K, int N, int lda, int ldw, int ldc,
    size_t zsA, size_t zsW, size_t zsC)
{
    A += (size_t)blockIdx.z * zsA;
    W += (size_t)blockIdx.z * zsW;
    C += (size_t)blockIdx.z * zsC;

    __shared__ unsigned short As[128 * 32];
    __shared__ unsigned short Ws[128 * 32];
    const int t    = threadIdx.x;
    const int wave = t >> 6, lane = t & 63;
    const int wm   = wave >> 1, wn = wave & 1;
    int bx, by;
    xcd_swizzle(bx, by);
    const int m0 = by * 128, n0 = bx * 128;

    floatx4 acc[4][4];
#pragma unroll
    for (int i = 0; i < 4; i++)
#pragma unroll
        for (int j = 0; j < 4; j++) acc[i][j] = (floatx4)0.f;

    const int lrow = lane >> 2;
    const int lcol = (lane & 3) * 8;
    const unsigned short* Ag = A + (size_t)(m0 + wave * 32 + lrow) * lda + lcol;
    const unsigned short* Wg = W + (size_t)(n0 + wave * 32 + lrow) * ldw + lcol;
    unsigned short* Asw = &As[wave * 32 * 32];
    unsigned short* Wsw = &Ws[wave * 32 * 32];
    const size_t rowskipA = (size_t)16 * lda;
    const size_t rowskipW = (size_t)16 * ldw;

    const int arow  = lane & 15;
    const int aquad = (lane >> 4) * 8;

    for (int k0 = 0; k0 < K; k0 += 32) {
        load_lds16(Ag + k0,             Asw);
        load_lds16(Ag + k0 + rowskipA,  Asw + 16 * 32);
        load_lds16(Wg + k0,             Wsw);
        load_lds16(Wg + k0 + rowskipW,  Wsw + 16 * 32);
        __syncthreads();

        bf16x8 af[4], wf[4];
#pragma unroll
        for (int mi = 0; mi < 4; mi++)
            af[mi] = *(const bf16x8*)&As[(wm * 64 + mi * 16 + arow) * 32 + aquad];
#pragma unroll
        for (int ni = 0; ni < 4; ni++)
            wf[ni] = *(const bf16x8*)&Ws[(wn * 64 + ni * 16 + arow) * 32 + aquad];
#pragma unroll
        for (int mi = 0; mi < 4; mi++)
#pragma unroll
            for (int ni = 0; ni < 4; ni++)
                acc[mi][ni] = __builtin_amdgcn_mfma_f32_16x16x32_bf16(
                    af[mi], wf[ni], acc[mi][ni], 0, 0, 0);
        __syncthreads();
    }

    const int crow = (lane >> 4) * 4, ccol = lane & 15;
#pragma unroll
    for (int mi = 0; mi < 4; mi++) {
#pragma unroll
        for (int ni = 0; ni < 4; ni++) {
            const int gm = m0 + wm * 64 + mi * 16 + crow;
            const int gn = n0 + wn * 64 + ni * 16 + ccol;
            float bb = 0.f;
            if constexpr (HAS_BIAS) bb = bias[gn];
#pragma unroll
            for (int r = 0; r < 4; r++) {
                float v = acc[mi][ni][r] + bb;
                if constexpr (sizeof(CT) == 2)
                    C[(size_t)(gm + r) * ldc + gn] = (CT)f32_to_bf16(v);
                else
                    C[(size_t)(gm + r) * ldc + gn] = v;
            }
        }
    }
}

// ---------------------------------------------------------------------------
// memsc: mem_scores[s,h,l] = ( U[h,s,:].ri[s,l,:] + qcol[s,h,:].bk[h,:] )*SCALE
// grid = 2048 (one block per s).
// ---------------------------------------------------------------------------
#define RI_STRIDE 1032    // padded ushort row stride: spreads l over banks

__global__ __launch_bounds__(256) void memsc_kernel(
    const unsigned short* __restrict__ U, const unsigned short* __restrict__ ri,
    const unsigned short* __restrict__ qkv4, const float* __restrict__ bqkv,
    float* __restrict__ scores)
{
    const int s = blockIdx.x;
    const int t = threadIdx.x;
    __shared__ unsigned short riS[LL * RI_STRIDE];
    __shared__ float qbS[H];
    // stage ri[s] : 8 rows x 1024
    {
        const unsigned short* src = ri + (size_t)s * (LL * D);
#pragma unroll
        for (int j = 0; j < 4; j++) {
            const int off = (j * 256 + t) * 8;        // 0..8191
            const int l = off >> 10, c = off & 1023;
            ushort8 v = *(const ushort8*)(src + off);
            *(ushort8*)&riS[l * RI_STRIDE + c] = v;
        }
    }
    // qb[h] = qcol[s,h,:] . bk[h,:]
    {
        const int h = t >> 4, sub = t & 15;
        const unsigned short* qc = qkv4 + (size_t)s * 4096 + 3 * D + h * HD + sub * 4;
        const float* bk = bqkv + D + h * HD + sub * 4;
        float acc = 0.f;
#pragma unroll
        for (int j = 0; j < 4; j++) acc += bf2f(qc[j]) * bk[j];
#pragma unroll
        for (int off = 1; off < 16; off <<= 1) acc += __shfl_xor(acc, off);
        if (sub == 0) qbS[h] = acc;
    }
    __syncthreads();
    // 128 (h,l) pairs x 2 half-threads each, 512-wide dot per thread
    const int p = t >> 1, half = t & 1;
    const int h = p >> 3, l = p & 7;
    const unsigned short* Up = U + ((size_t)h * SEQ + s) * D + half * 512;
    const unsigned short* rp = &riS[l * RI_STRIDE + half * 512];
    float acc = 0.f;
#pragma unroll 4
    for (int j = 0; j < 64; j++) {
        ushort8 u = *(const ushort8*)(Up + j * 8);
        ushort8 r = *(const ushort8*)(rp + j * 8);
#pragma unroll
        for (int k = 0; k < 8; k++) acc += bf2f(u[k]) * bf2f(r[k]);
    }
    acc += __shfl_xor(acc, 1);
    if (half == 0)
        scores[((size_t)s * H + h) * LL + l] = (acc + qbS[h]) * SCALE;
}

// ---------------------------------------------------------------------------
// Split-K MFMA flash dual attention (token keys only). Split 0 folds the 8
// precomputed memory-key scores into (m,l) and writes unnormalized mem
// weights memP. Partials (O,m,l) -> workspace.
// ---------------------------------------------------------------------------
union AttnShared {
    struct { unsigned short Qs[64 * 72]; unsigned short Ks[64 * 72]; } qk;
    float Osp[64 * 68];
};

__global__ __launch_bounds__(256) void attn_split_kernel(
    const unsigned short* __restrict__ qkv4,
    const float* __restrict__ mem_scores, float* __restrict__ memP,
    float* __restrict__ Opart, float2* __restrict__ mlpart)
{
    const int t    = threadIdx.x;
    const int w    = t >> 6, lane = t & 63;
    const int lrow = lane & 15;
    const int lk   = (lane >> 4) * 8;
    const int rrow = (lane >> 4) * 4;
    const int lin  = blockIdx.x;
    const int hs   = lin & 31, g = lin >> 5;
    const int h    = hs >> 1, s = hs & 1;
    const int a    = g & 7, bq = g >> 3;
    const int qt   = (bq == 0) ? a : (bq == 1) ? 15 - a : (bq == 2) ? 16 + a : 31 - a;
    const int q0   = qt * 64;
    const int n    = qt + 1, nh = (n + 1) >> 1;
    const int lo   = s ? nh : 0, hi = s ? n : nh;
    const int part = (h * 32 + qt) * 2 + s;

    __shared__ AttnShared U;
    __shared__ unsigned short Vt[64 * 72];   // [e][key]
    __shared__ unsigned short Pb[64 * 72];   // P bf16 [q][key]
    __shared__ float row_m[64], row_l[64];
    __shared__ float mem_mm[64], mem_alpha[64], mem_suml[64];

    // stage Q [q][e]
#pragma unroll
    for (int p = 0; p < 2; p++) {
        int idx = p * 256 + t;
        int row = idx >> 3, col = (idx & 7) * 8;
        *(bf16x8*)&U.qk.Qs[row * 72 + col] =
            *(const bf16x8*)(qkv4 + (size_t)(q0 + row) * 4096 + h * HD + col);
    }

    float m_i[4], l_i[4];
    floatx4 Oacc[4];
#pragma unroll
    for (int r = 0; r < 4; r++) { m_i[r] = -1e30f; l_i[r] = 0.f; }
#pragma unroll
    for (int et = 0; et < 4; et++) Oacc[et] = (floatx4)0.f;

    for (int jt = lo; jt < hi; jt++) {
        const int j0 = jt * 64;
        // stage K [key][e]
#pragma unroll
        for (int p = 0; p < 2; p++) {
            int idx = p * 256 + t;
            int row = idx >> 3, col = (idx & 7) * 8;
            *(bf16x8*)&U.qk.Ks[row * 72 + col] =
                *(const bf16x8*)(qkv4 + (size_t)(j0 + row) * 4096 + D + h * HD + col);
        }
        // stage V transposed -> Vt[e][key]
        {
            const int pr = t & 31, eg = t >> 5;
            const unsigned short* v0 =
                qkv4 + (size_t)(j0 + 2 * pr) * 4096 + 2 * D + h * HD + eg * 8;
            ushort8 va = *(const ushort8*)v0;
            ushort8 vb = *(const ushort8*)(v0 + 4096);
#pragma unroll
            for (int j = 0; j < 8; j++) {
                unsigned int pk = (unsigned int)va[j] | ((unsigned int)vb[j] << 16);
                *(unsigned int*)&Vt[(eg * 8 + j) * 72 + 2 * pr] = pk;
            }
        }
        __syncthreads();

        // S = Q K^T
        floatx4 S[4];
#pragma unroll
        for (int nt = 0; nt < 4; nt++) S[nt] = (floatx4)0.f;
#pragma unroll
        for (int kst = 0; kst < 2; kst++) {
            bf16x8 aq = *(const bf16x8*)&U.qk.Qs[(w * 16 + lrow) * 72 + kst * 32 + lk];
#pragma unroll
            for (int nt = 0; nt < 4; nt++) {
                bf16x8 bk = *(const bf16x8*)&U.qk.Ks[(nt * 16 + lrow) * 72 + kst * 32 + lk];
                S[nt] = __builtin_amdgcn_mfma_f32_16x16x32_bf16(aq, bk, S[nt], 0, 0, 0);
            }
        }

        // online softmax; P -> Pb (bf16)
#pragma unroll
        for (int r = 0; r < 4; r++) {
            const int qg = q0 + w * 16 + rrow + r;
            float sc[4];
            float mx = -1e30f;
#pragma unroll
            for (int nt = 0; nt < 4; nt++) {
                sc[nt] = S[nt][r] * SCALE;
                if (j0 + nt * 16 + lrow > qg) sc[nt] = -1e30f;
                mx = fmaxf(mx, sc[nt]);
            }
#pragma unroll
            for (int off = 1; off < 16; off <<= 1)
                mx = fmaxf(mx, __shfl_xor(mx, off));
            if (mx <= -1e29f) {
                // entire tile masked for this row (split-1 early rows)
#pragma unroll
                for (int nt = 0; nt < 4; nt++)
                    Pb[(w * 16 + rrow + r) * 72 + nt * 16 + lrow] = 0;
                continue;
            }
            const float newm  = fmaxf(m_i[r], mx);
            const float alpha = __expf(m_i[r] - newm);
            m_i[r] = newm;
            float ps = 0.f;
#pragma unroll
            for (int nt = 0; nt < 4; nt++) {
                float pe = __expf(sc[nt] - newm);
                ps += pe;
                Pb[(w * 16 + rrow + r) * 72 + nt * 16 + lrow] = f32_to_bf16(pe);
            }
#pragma unroll
            for (int off = 1; off < 16; off <<= 1)
                ps += __shfl_xor(ps, off);
            l_i[r] = l_i[r] * alpha + ps;
#pragma unroll
            for (int et = 0; et < 4; et++) Oacc[et][r] *= alpha;
        }
        __syncthreads();

        // O += P @ V
#pragma unroll
        for (int kst = 0; kst < 2; kst++) {
            bf16x8 ap = *(const bf16x8*)&Pb[(w * 16 + lrow) * 72 + kst * 32 + lk];
#pragma unroll
            for (int et = 0; et < 4; et++) {
                bf16x8 bv = *(const bf16x8*)&Vt[(et * 16 + lrow) * 72 + kst * 32 + lk];
                Oacc[et] = __builtin_amdgcn_mfma_f32_16x16x32_bf16(ap, bv, Oacc[et], 0, 0, 0);
            }
        }
        __syncthreads();
    }

    if (s == 1) {
        // write partials straight from registers
#pragma unroll
        for (int r = 0; r < 4; r++) {
            const int ql = w * 16 + rrow + r;
            if (lrow == 0) mlpart[(size_t)part * 64 + ql] = make_float2(m_i[r], l_i[r]);
#pragma unroll
            for (int et = 0; et < 4; et++)
                Opart[((size_t)part * 64 + ql) * 64 + et * 16 + lrow] = Oacc[et][r];
        }
        return;
    }

    // ---- split 0: fold precomputed memory-key scores, then write partials ----
#pragma unroll
    for (int r = 0; r < 4; r++) {
        const int ql = w * 16 + rrow + r;
        if (lrow == 0) { row_m[ql] = m_i[r]; row_l[ql] = l_i[r]; }
#pragma unroll
        for (int et = 0; et < 4; et++)
            U.Osp[ql * 68 + et * 16 + lrow] = Oacc[et][r];
    }
    __syncthreads();

    if (t < 64) {
        const int qi = t, qg = q0 + qi;
        const float* msp = mem_scores + ((size_t)qg * H + h) * LL;
        float ms[LL];
#pragma unroll
        for (int l = 0; l < LL; l++) ms[l] = msp[l];    // already scaled
        const float mo = row_m[qi];
        float mm = mo;
#pragma unroll
        for (int l = 0; l < LL; l++) mm = fmaxf(mm, ms[l]);
        const float alpha = __expf(mo - mm);
        float suml = 0.f;
        float* mp = memP + ((size_t)qg * H + h) * LL;
#pragma unroll
        for (int l = 0; l < LL; l++) {
            float pe = __expf(ms[l] - mm);
            suml += pe;
            mp[l] = pe;
        }
        mem_mm[qi] = mm; mem_alpha[qi] = alpha; mem_suml[qi] = suml;
    }
    __syncthreads();

    {
        const int tx = t & 15, ty = t >> 4;
#pragma unroll
        for (int i = 0; i < 4; i++) {
            const int qi = ty * 4 + i;
            const float alpha = mem_alpha[qi];
            const float lf = row_l[qi] * alpha + mem_suml[qi];
            float4 o = *(const float4*)&U.Osp[qi * 68 + tx * 4];
            o.x *= alpha; o.y *= alpha; o.z *= alpha; o.w *= alpha;
            *(float4*)&Opart[((size_t)part * 64 + qi) * 64 + tx * 4] = o;
            if (tx == 0) mlpart[(size_t)part * 64 + qi] = make_float2(mem_mm[qi], lf);
        }
    }
}

// ---------------------------------------------------------------------------
// merge: combine the two key-split partials per (h, qt), normalize.
// Writes token context (f32), final normalized mem weights mwf, and
// Pmem[s,h] = sum_l mwf (for the bv bias term).
// ---------------------------------------------------------------------------
__global__ __launch_bounds__(256) void attn_merge_kernel(
    const float* __restrict__ Opart, const float2* __restrict__ mlpart,
    const float* __restrict__ memP,
    float* __restrict__ tok, float* __restrict__ mwf, float* __restrict__ Pmem)
{
    const int blk = blockIdx.x;            // h*32 + qt
    const int h = blk >> 5, qt = blk & 31;
    const int q0 = qt * 64;
    const int t = threadIdx.x, tx = t & 15, ty = t >> 4;
    const size_t p0 = (size_t)blk * 2, p1 = p0 + 1;
#pragma unroll
    for (int i = 0; i < 4; i++) {
        const int qi = ty * 4 + i, qg = q0 + qi;
        float2 ml0 = mlpart[p0 * 64 + qi];
        float2 ml1 = mlpart[p1 * 64 + qi];
        const float M  = fmaxf(ml0.x, ml1.x);
        const float f0 = __expf(ml0.x - M), f1 = __expf(ml1.x - M);
        const float rl = 1.f / (ml0.y * f0 + ml1.y * f1);
        float4 o0 = *(const float4*)&Opart[(p0 * 64 + qi) * 64 + tx * 4];
        float4 o1 = *(const float4*)&Opart[(p1 * 64 + qi) * 64 + tx * 4];
        float4 o;
        o.x = (o0.x * f0 + o1.x * f1) * rl;
        o.y = (o0.y * f0 + o1.y * f1) * rl;
        o.z = (o0.z * f0 + o1.z * f1) * rl;
        o.w = (o0.w * f0 + o1.w * f1) * rl;
        *(float4*)&tok[(size_t)qg * D + h * HD + tx * 4] = o;
        if (tx == 0) {
            const float w0 = f0 * rl;      // memP carried split-0's running max
            const float* mp = memP + ((size_t)qg * H + h) * LL;
            float* mw = mwf + ((size_t)qg * H + h) * LL;
            float psum = 0.f;
#pragma unroll
            for (int l = 0; l < LL; l++) { float v = mp[l] * w0; mw[l] = v; psum += v; }
            Pmem[(size_t)qg * H + h] = psum;
        }
    }
}

// ---------------------------------------------------------------------------
// rbar[h,s,:] = sum_l mwf[s,h,l] * ri[s*8+l,:]   (bf16 out). grid = 2048 (s).
// ---------------------------------------------------------------------------
__global__ __launch_bounds__(256) void rbar_kernel(
    const float* __restrict__ mwf, const unsigned short* __restrict__ ri,
    unsigned short* __restrict__ rbar)
{
    const int s = blockIdx.x, t = threadIdx.x;
    __shared__ unsigned short riS[LL * D];
    __shared__ float wS[H * LL];
    {
        const unsigned short* src = ri + (size_t)s * (LL * D);
#pragma unroll
        for (int j = 0; j < 4; j++) {
            const int off = (j * 256 + t) * 8;
            *(ushort8*)&riS[off] = *(const ushort8*)(src + off);
        }
    }
    if (t < H * LL) wS[t] = mwf[(size_t)s * (H * LL) + t];
    __syncthreads();
    const int c4 = t * 4;
#pragma unroll
    for (int hh = 0; hh < H; hh++) {
        float v0 = 0.f, v1 = 0.f, v2 = 0.f, v3 = 0.f;
#pragma unroll
        for (int l = 0; l < LL; l++) {
            const float wv = wS[hh * LL + l];
            ushort4 rr = *(const ushort4*)&riS[l * D + c4];
            v0 += wv * bf2f(rr.x); v1 += wv * bf2f(rr.y);
            v2 += wv * bf2f(rr.z); v3 += wv * bf2f(rr.w);
        }
        ushort4 o;
        o.x = f32_to_bf16(v0); o.y = f32_to_bf16(v1);
        o.z = f32_to_bf16(v2); o.w = f32_to_bf16(v3);
        *(ushort4*)(rbar + ((size_t)hh * SEQ + s) * D + c4) = o;
    }
}

// ---------------------------------------------------------------------------
// ctx GEMM: ctx[s, h*64+e] = bf16( rbar[h,s,:] . Wv[h*64+e,:]
//                                  + bv[h*64+e]*Pmem[s,h] + tok[s,h*64+e] )
// 128(M)x64(N) tile, BK=32, 4 waves (wave = m-subtile). grid = (16 mt, 16 h).
// ---------------------------------------------------------------------------
__global__ __launch_bounds__(256) void gemm_ctx_kernel(
    const unsigned short* __restrict__ rbar, const unsigned short* __restrict__ W4,
    const float* __restrict__ bqkv, const float* __restrict__ Pmem,
    const float* __restrict__ tok, unsigned short* __restrict__ ctx)
{
    const int mt = blockIdx.x;      // 0..15
    const int h  = blockIdx.y;      // 0..15
    const unsigned short* A  = rbar + (size_t)h * SEQ * D + (size_t)mt * 128 * D;
    const unsigned short* Wv = W4 + (size_t)(2 * D + h * HD) * D;   // 64 rows x 1024
    const float* bv = bqkv + 2 * D + h * HD;

    __shared__ unsigned short As[128 * 32];
    __shared__ unsigned short Ws[64 * 32];
    const int t    = threadIdx.x;
    const int wave = t >> 6, lane = t & 63;

    floatx4 acc[2][4];
#pragma unroll
    for (int i = 0; i < 2; i++)
#pragma unroll
        for (int j = 0; j < 4; j++) acc[i][j] = (floatx4)0.f;

    const int lrow = lane >> 2;
    const int lcol = (lane & 3) * 8;
    const unsigned short* Ag = A  + (size_t)(wave * 32 + lrow) * D + lcol;
    const unsigned short* Wg = Wv + (size_t)(wave * 32 + lrow) * D + lcol;  // waves 0,1 only
    unsigned short* Asw = &As[wave * 32 * 32];
    unsigned short* Wsw = &Ws[wave * 32 * 32];
    const size_t rowskip = (size_t)16 * D;

    const int arow  = lane & 15;
    const int aquad = (lane >> 4) * 8;

    for (int k0 = 0; k0 < D; k0 += 32) {
        load_lds16(Ag + k0,           Asw);
        load_lds16(Ag + k0 + rowskip, Asw + 16 * 32);
        if (wave < 2) {
            load_lds16(Wg + k0,           Wsw);
            load_lds16(Wg + k0 + rowskip, Wsw + 16 * 32);
        }
        __syncthreads();

        bf16x8 af[2], wf[4];
#pragma unroll
        for (int mi = 0; mi < 2; mi++)
            af[mi] = *(const bf16x8*)&As[(wave * 32 + mi * 16 + arow) * 32 + aquad];
#pragma unroll
        for (int ni = 0; ni < 4; ni++)
            wf[ni] = *(const bf16x8*)&Ws[(ni * 16 + arow) * 32 + aquad];
#pragma unroll
        for (int mi = 0; mi < 2; mi++)
#pragma unroll
            for (int ni = 0; ni < 4; ni++)
                acc[mi][ni] = __builtin_amdgcn_mfma_f32_16x16x32_bf16(
                    af[mi], wf[ni], acc[mi][ni], 0, 0, 0);
        __syncthreads();
    }

    const int crow = (lane >> 4) * 4, ccol = lane & 15;
#pragma unroll
    for (int mi = 0; mi < 2; mi++) {
#pragma unroll
        for (int ni = 0; ni < 4; ni++) {
            const int e  = ni * 16 + ccol;
            const float bb = bv[e];
#pragma unroll
            for (int r = 0; r < 4; r++) {
                const int grow = mt * 128 + wave * 32 + mi * 16 + crow + r;
                float v = acc[mi][ni][r] + bb * Pmem[(size_t)grow * H + h]
                          + tok[(size_t)grow * D + h * HD + e];
                ctx[(size_t)grow * D + h * HD + e] = f32_to_bf16(v);
            }
        }
    }
}

// ---------------------------------------------------------------------------
extern "C" void kernel_launch(void* const* d_in, const int* in_sizes, int n_in,
                              void* d_out, int out_size, void* d_ws, size_t ws_size,
                              hipStream_t stream)
{
    const float* x    = (const float*)d_in[0];
    const float* pv   = (const float*)d_in[1];
    const float* Wqkv = (const float*)d_in[2];
    const float* bqkv = (const float*)d_in[3];
    const float* Wcol = (const float*)d_in[4];
    const float* bcol = (const float*)d_in[5];
    const float* Wout = (const float*)d_in[6];
    const float* bout = (const float*)d_in[7];
    float* out = (float*)d_out;

    char* p = (char*)d_ws;
    unsigned short* x_bf    = (unsigned short*)p; p += (size_t)2048 * 1024 * 2;
    unsigned short* W4_bf   = (unsigned short*)p; p += (size_t)4096 * 1024 * 2;   // Wqkv | Wcol
    unsigned short* Wout_bf = (unsigned short*)p; p += (size_t)1024 * 1024 * 2;
    float*          b4      = (float*)p;          p += (size_t)4096 * 4;
    unsigned short* ri_bf   = (unsigned short*)p; p += (size_t)16384 * 1024 * 2;
    unsigned short* qkv4_bf = (unsigned short*)p; p += (size_t)2048 * 4096 * 2;   // Q|K|V|Qcol
    unsigned short* WkT_bf  = (unsigned short*)p; p += (size_t)16 * 1024 * 64 * 2;
    float*          scores  = (float*)p;          p += (size_t)2048 * 16 * 8 * 4;
    float*          memP    = (float*)p;          p += (size_t)2048 * 16 * 8 * 4;
    float*          mwf     = (float*)p;          p += (size_t)2048 * 16 * 8 * 4;
    float*          Pmem    = (float*)p;          p += (size_t)2048 * 16 * 4;
    float*          tok     = (float*)p;          p += (size_t)2048 * 1024 * 4;
    unsigned short* ctx_bf  = (unsigned short*)p; p += (size_t)2048 * 1024 * 2;
    float*          Opart   = (float*)p;          p += (size_t)1024 * 64 * 64 * 4;
    float2*         mlpart  = (float2*)p;         p += (size_t)1024 * 64 * 8;
    // U and rbar have disjoint lifetimes (U dead after memsc) -> share buffer
    unsigned short* Urb     = (unsigned short*)p; p += (size_t)16 * 2048 * 1024 * 2;
    // ~160 MB total

    // LN + all bf16 casts + bias concat
    prep_kernel<<<PREP_GRID, 256, 0, stream>>>(pv, x, Wqkv, Wcol, Wout, bqkv, bcol,
                                               ri_bf, x_bf, W4_bf, Wout_bf, b4);
    // per-head transposed Wk for the U GEMM
    wkt_kernel<<<256, 256, 0, stream>>>(Wqkv, WkT_bf);
    // qkv4 = x @ [Wqkv|Wcol]^T + [bqkv|bcol]   (fused, N=4096)
    gemm_bf16_kernel<unsigned short, true><<<dim3(32, 16, 1), 256, 0, stream>>>(
        x_bf, W4_bf, b4, qkv4_bf, 1024, 4096, 1024, 1024, 4096, 0, 0, 0);
    // U[h] = Qcol[h] @ Wk[h]   (K=64 head-batched; replaces the rk GEMM)
    gemm_bf16_kernel<unsigned short, false><<<dim3(8, 16, 16), 256, 0, stream>>>(
        qkv4_bf + 3 * D, WkT_bf, nullptr, Urb, 64, 1024, 4096, 64, 1024,
        (size_t)HD, (size_t)D * HD, (size_t)SEQ * D);
    // mem_scores = (U . ri + qcol.bk) * scale
    memsc_kernel<<<2048, 256, 0, stream>>>(Urb, ri_bf, qkv4_bf, bqkv, scores);
    // attention split + merge
    attn_split_kernel<<<1024, 256, 0, stream>>>(qkv4_bf, scores, memP, Opart, mlpart);
    attn_merge_kernel<<<512, 256, 0, stream>>>(Opart, mlpart, memP, tok, mwf, Pmem);
    // rbar = sum_l mwf * ri   (reuses U's buffer)
    rbar_kernel<<<2048, 256, 0, stream>>>(mwf, ri_bf, Urb);
    // ctx = tok + Wv[h] @ rbar[h] + bv*Pmem   (replaces the rv GEMM + fold)
    gemm_ctx_kernel<<<dim3(16, 16), 256, 0, stream>>>(Urb, W4_bf, bqkv, Pmem, tok, ctx_bf);
    // out = ctx @ Wout^T + bout
    gemm_bf16_kernel<float, true><<<dim3(8, 16, 1), 256, 0, stream>>>(
        ctx_bf, Wout_bf, bout, out, 1024, 1024, 1024, 1024, 1024, 0, 0, 0);
}

// Round 2
// 343.747 us; speedup vs baseline: 1.0632x; 1.0632x over previous
//
#include <hip/hip_runtime.h>
#include <math.h>

#define D   1024
#define H   16
#define HD  64
#define SEQ 2048
#define LL  8
#define SCALE 0.125f

typedef __attribute__((ext_vector_type(8))) __bf16 bf16x8;
typedef __attribute__((ext_vector_type(4))) float floatx4;
typedef __attribute__((ext_vector_type(8))) unsigned short ushort8;

__device__ inline unsigned short f32_to_bf16(float f) {
    unsigned int u = __builtin_bit_cast(unsigned int, f);
    u += 0x7FFF + ((u >> 16) & 1);   // round-to-nearest-even
    return (unsigned short)(u >> 16);
}
__device__ inline float bf2f(unsigned short u) {
    unsigned int x = (unsigned int)u << 16;
    return __builtin_bit_cast(float, x);
}
__device__ inline void load_lds16(const void* g, void* l) {
    __builtin_amdgcn_global_load_lds(
        (__attribute__((address_space(1))) void*)g,
        (__attribute__((address_space(3))) void*)l, 16, 0, 0);
}

// XCD-aware swizzle: contiguous grid chunk per XCD -> A-panel L2 reuse.
__device__ inline void xcd_swizzle(int& bx, int& by) {
    const int gx   = gridDim.x;
    const int lin  = blockIdx.y * gx + blockIdx.x;
    const int nblk = gx * gridDim.y;
    const int virt = (lin & 7) * (nblk >> 3) + (lin >> 3);
    bx = virt % gx;
    by = virt / gx;
}

// ---------------------------------------------------------------------------
// prep: LN(reproject(pv)) -> ri_bf  |  f32->bf16 of x, Wqkv|Wcol (->W4), Wout
//       |  bias concat b4 = [bqkv, bcol]
// ---------------------------------------------------------------------------
#define NQ_X    524288
#define NQ_WQKV 786432
#define NQ_WC   262144
#define NQ_WO   262144
#define LN_BLK  16384
#define CVT_BLK 7168          // (NQ_X+NQ_WQKV+NQ_WC+NQ_WO)/256
#define PREP_GRID (LN_BLK + CVT_BLK + 4)

__global__ __launch_bounds__(256) void prep_kernel(
    const float* __restrict__ pv, const float* __restrict__ x,
    const float* __restrict__ Wqkv, const float* __restrict__ Wcol,
    const float* __restrict__ Wout, const float* __restrict__ bqkv,
    const float* __restrict__ bcol,
    unsigned short* __restrict__ ri, unsigned short* __restrict__ xb,
    unsigned short* __restrict__ W4b, unsigned short* __restrict__ Woutb,
    float* __restrict__ b4)
{
    const int b = blockIdx.x;
    const int t = threadIdx.x;
    if (b < LN_BLK) {
        // LayerNorm row r = s*L + l over d=1024
        const int r = b;
        const int s = r >> 3, l = r & 7;
        const int h = t >> 4, e = (t & 15) * 4;
        const size_t src = (size_t)l * (H * SEQ * HD) + (size_t)h * (SEQ * HD)
                         + (size_t)s * HD + e;
        float4 v = *(const float4*)(pv + src);
        float sum = v.x + v.y + v.z + v.w;
        float sq  = v.x * v.x + v.y * v.y + v.z * v.z + v.w * v.w;
#pragma unroll
        for (int off = 32; off; off >>= 1) {
            sum += __shfl_xor(sum, off);
            sq  += __shfl_xor(sq, off);
        }
        __shared__ float red[8];
        if ((t & 63) == 0) { red[(t >> 6) * 2] = sum; red[(t >> 6) * 2 + 1] = sq; }
        __syncthreads();
        sum = red[0] + red[2] + red[4] + red[6];
        sq  = red[1] + red[3] + red[5] + red[7];
        const float mean = sum * (1.f / 1024.f);
        const float var  = sq * (1.f / 1024.f) - mean * mean;
        const float rstd = rsqrtf(var + 1e-5f);
        ushort4 o;
        o.x = f32_to_bf16((v.x - mean) * rstd);
        o.y = f32_to_bf16((v.y - mean) * rstd);
        o.z = f32_to_bf16((v.z - mean) * rstd);
        o.w = f32_to_bf16((v.w - mean) * rstd);
        *(ushort4*)(ri + (size_t)r * D + t * 4) = o;
    } else if (b < LN_BLK + CVT_BLK) {
        const int i = (b - LN_BLK) * 256 + t;
        const float* src; unsigned short* dst; int off;
        if (i < NQ_X)                        { src = x;    dst = xb;    off = i; }
        else if (i < NQ_X + NQ_WQKV)         { src = Wqkv; dst = W4b;   off = i - NQ_X; }
        else if (i < NQ_X + NQ_WQKV + NQ_WC) {
            float4 v = ((const float4*)Wcol)[i - NQ_X - NQ_WQKV];
            ushort4 o;
            o.x = f32_to_bf16(v.x); o.y = f32_to_bf16(v.y);
            o.z = f32_to_bf16(v.z); o.w = f32_to_bf16(v.w);
            ((ushort4*)(W4b))[NQ_WQKV + (i - NQ_X - NQ_WQKV)] = o;
            return;
        }
        else                                 { src = Wout; dst = Woutb; off = i - NQ_X - NQ_WQKV - NQ_WC; }
        float4 v = ((const float4*)src)[off];
        ushort4 o;
        o.x = f32_to_bf16(v.x); o.y = f32_to_bf16(v.y);
        o.z = f32_to_bf16(v.z); o.w = f32_to_bf16(v.w);
        ((ushort4*)dst)[off] = o;
    } else {
        // bias concat: 1024 float4 quads, first 768 from bqkv, rest from bcol
        const int q = (b - LN_BLK - CVT_BLK) * 256 + t;
        float4 v = (q < 768) ? ((const float4*)bqkv)[q] : ((const float4*)bcol)[q - 768];
        ((float4*)b4)[q] = v;
    }
}

// ---------------------------------------------------------------------------
// wkt: WkT[h][c][e] = Wqkv[1024 + h*64 + e][c]  (bf16). Grid 256 = 16h x 16ct.
// ---------------------------------------------------------------------------
__global__ __launch_bounds__(256) void wkt_kernel(
    const float* __restrict__ Wqkv, unsigned short* __restrict__ WkT)
{
    const int h = blockIdx.x >> 4, ct = blockIdx.x & 15;
    const int c0 = ct * 64;
    const int t = threadIdx.x;
    __shared__ float tile[64][68];
    {
        const int e  = t >> 2;            // 0..63
        const int c4 = (t & 3) * 16;      // 0,16,32,48
        const float* src = Wqkv + (size_t)(D + h * HD + e) * D + c0 + c4;
#pragma unroll
        for (int j = 0; j < 4; j++) {
            float4 v = ((const float4*)src)[j];
            *(float4*)&tile[e][c4 + j * 4] = v;
        }
    }
    __syncthreads();
    {
        const int c  = t >> 2;            // local col 0..63
        const int e0 = (t & 3) * 16;      // 0,16,32,48
        ushort8 o0, o1;
#pragma unroll
        for (int j = 0; j < 8; j++) o0[j] = f32_to_bf16(tile[e0 + j][c]);
#pragma unroll
        for (int j = 0; j < 8; j++) o1[j] = f32_to_bf16(tile[e0 + 8 + j][c]);
        unsigned short* dst = WkT + (size_t)h * (D * HD) + (size_t)(c0 + c) * HD + e0;
        *(ushort8*)dst       = o0;
        *(ushort8*)(dst + 8) = o1;
    }
}

// ---------------------------------------------------------------------------
// bf16 MFMA GEMM: C[M,N] = A[M,K] @ W[N,K]^T (+ bias[N]). CT = float or ushort.
// 128x128 tile, BK=32, 4 waves, 4x4 16x16x32 MFMAs per wave. XCD-swizzled.
// Generalized: lda/ldw/ldc row strides, blockIdx.z batching via element strides.
// ---------------------------------------------------------------------------
template <typename CT, bool HAS_BIAS>
__global__ __launch_bounds__(256) void gemm_bf16_kernel(
    const unsigned short* __restrict__ A, const unsigned short* __restrict__ W,
    const float* __restrict__ bias, CT* __restrict__ C,
    int K, int N, int lda, int ldw, int ldc,
    size_t zsA, size_t zsW, size_t zsC)
{
    A += (size_t)blockIdx.z * zsA;
    W += (size_t)blockIdx.z * zsW;
    C += (size_t)blockIdx.z * zsC;

    __shared__ unsigned short As[128 * 32];
    __shared__ unsigned short Ws[128 * 32];
    const int t    = threadIdx.x;
    const int wave = t >> 6, lane = t & 63;
    const int wm   = wave >> 1, wn = wave & 1;
    int bx, by;
    xcd_swizzle(bx, by);
    const int m0 = by * 128, n0 = bx * 128;

    floatx4 acc[4][4];
#pragma unroll
    for (int i = 0; i < 4; i++)
#pragma unroll
        for (int j = 0; j < 4; j++) acc[i][j] = (floatx4)0.f;

    const int lrow = lane >> 2;
    const int lcol = (lane & 3) * 8;
    const unsigned short* Ag = A + (size_t)(m0 + wave * 32 + lrow) * lda + lcol;
    const unsigned short* Wg = W + (size_t)(n0 + wave * 32 + lrow) * ldw + lcol;
    unsigned short* Asw = &As[wave * 32 * 32];
    unsigned short* Wsw = &Ws[wave * 32 * 32];
    const size_t rowskipA = (size_t)16 * lda;
    const size_t rowskipW = (size_t)16 * ldw;

    const int arow  = lane & 15;
    const int aquad = (lane >> 4) * 8;

    for (int k0 = 0; k0 < K; k0 += 32) {
        load_lds16(Ag + k0,             Asw);
        load_lds16(Ag + k0 + rowskipA,  Asw + 16 * 32);
        load_lds16(Wg + k0,             Wsw);
        load_lds16(Wg + k0 + rowskipW,  Wsw + 16 * 32);
        __syncthreads();

        bf16x8 af[4], wf[4];
#pragma unroll
        for (int mi = 0; mi < 4; mi++)
            af[mi] = *(const bf16x8*)&As[(wm * 64 + mi * 16 + arow) * 32 + aquad];
#pragma unroll
        for (int ni = 0; ni < 4; ni++)
            wf[ni] = *(const bf16x8*)&Ws[(wn * 64 + ni * 16 + arow) * 32 + aquad];
#pragma unroll
        for (int mi = 0; mi < 4; mi++)
#pragma unroll
            for (int ni = 0; ni < 4; ni++)
                acc[mi][ni] = __builtin_amdgcn_mfma_f32_16x16x32_bf16(
                    af[mi], wf[ni], acc[mi][ni], 0, 0, 0);
        __syncthreads();
    }

    const int crow = (lane >> 4) * 4, ccol = lane & 15;
#pragma unroll
    for (int mi = 0; mi < 4; mi++) {
#pragma unroll
        for (int ni = 0; ni < 4; ni++) {
            const int gm = m0 + wm * 64 + mi * 16 + crow;
            const int gn = n0 + wn * 64 + ni * 16 + ccol;
            float bb = 0.f;
            if constexpr (HAS_BIAS) bb = bias[gn];
#pragma unroll
            for (int r = 0; r < 4; r++) {
                float v = acc[mi][ni][r] + bb;
                if constexpr (sizeof(CT) == 2)
                    C[(size_t)(gm + r) * ldc + gn] = (CT)f32_to_bf16(v);
                else
                    C[(size_t)(gm + r) * ldc + gn] = v;
            }
        }
    }
}

// ---------------------------------------------------------------------------
// memsc: mem_scores[s,h,l] = ( U[h,s,:].ri[s,l,:] + qcol[s,h,:].bk[h,:] )*SCALE
// grid = 2048 (one block per s).
// ---------------------------------------------------------------------------
#define RI_STRIDE 1032    // padded ushort row stride: spreads l over banks

__global__ __launch_bounds__(256) void memsc_kernel(
    const unsigned short* __restrict__ U, const unsigned short* __restrict__ ri,
    const unsigned short* __restrict__ qkv4, const float* __restrict__ bqkv,
    float* __restrict__ scores)
{
    const int s = blockIdx.x;
    const int t = threadIdx.x;
    __shared__ unsigned short riS[LL * RI_STRIDE];
    __shared__ float qbS[H];
    // stage ri[s] : 8 rows x 1024
    {
        const unsigned short* src = ri + (size_t)s * (LL * D);
#pragma unroll
        for (int j = 0; j < 4; j++) {
            const int off = (j * 256 + t) * 8;        // 0..8191
            const int l = off >> 10, c = off & 1023;
            ushort8 v = *(const ushort8*)(src + off);
            *(ushort8*)&riS[l * RI_STRIDE + c] = v;
        }
    }
    // qb[h] = qcol[s,h,:] . bk[h,:]
    {
        const int h = t >> 4, sub = t & 15;
        const unsigned short* qc = qkv4 + (size_t)s * 4096 + 3 * D + h * HD + sub * 4;
        const float* bk = bqkv + D + h * HD + sub * 4;
        float acc = 0.f;
#pragma unroll
        for (int j = 0; j < 4; j++) acc += bf2f(qc[j]) * bk[j];
#pragma unroll
        for (int off = 1; off < 16; off <<= 1) acc += __shfl_xor(acc, off);
        if (sub == 0) qbS[h] = acc;
    }
    __syncthreads();
    // 128 (h,l) pairs x 2 half-threads each, 512-wide dot per thread
    const int p = t >> 1, half = t & 1;
    const int h = p >> 3, l = p & 7;
    const unsigned short* Up = U + ((size_t)h * SEQ + s) * D + half * 512;
    const unsigned short* rp = &riS[l * RI_STRIDE + half * 512];
    float acc = 0.f;
#pragma unroll 4
    for (int j = 0; j < 64; j++) {
        ushort8 u = *(const ushort8*)(Up + j * 8);
        ushort8 r = *(const ushort8*)(rp + j * 8);
#pragma unroll
        for (int k = 0; k < 8; k++) acc += bf2f(u[k]) * bf2f(r[k]);
    }
    acc += __shfl_xor(acc, 1);
    if (half == 0)
        scores[((size_t)s * H + h) * LL + l] = (acc + qbS[h]) * SCALE;
}

// ---------------------------------------------------------------------------
// Split-K MFMA flash dual attention (token keys only), 4-way key split.
// Q in registers; K/V reg-prefetch (T14); 2 barriers per tile; setprio (T5).
// Split 0 folds the 8 precomputed memory-key scores and writes memP.
// Partials (O,m,l) -> workspace; empty splits write (m=-1e30,l=0,O=0).
// ---------------------------------------------------------------------------
__global__ __launch_bounds__(256) void attn_split_kernel(
    const unsigned short* __restrict__ qkv4,
    const float* __restrict__ mem_scores, float* __restrict__ memP,
    float* __restrict__ Opart, float2* __restrict__ mlpart)
{
    const int t    = threadIdx.x;
    const int w    = t >> 6, lane = t & 63;
    const int lrow = lane & 15;
    const int lk   = (lane >> 4) * 8;
    const int rrow = (lane >> 4) * 4;
    const int lin  = blockIdx.x;
    const int hsp  = lin & 63, g = lin >> 6;
    const int h    = hsp >> 2, s = hsp & 3;
    const int a    = g & 7, bq = g >> 3;
    const int qt   = (bq == 0) ? a : (bq == 1) ? 15 - a : (bq == 2) ? 16 + a : 31 - a;
    const int q0   = qt * 64;
    const int n    = qt + 1;
    const int lo   = (s * n) >> 2, hi = ((s + 1) * n) >> 2;
    const int part = (h * 32 + qt) * 4 + s;

    __shared__ unsigned short Ks[64 * 72];   // [key][e]
    __shared__ unsigned short Vt[64 * 72];   // [e][key]
    __shared__ unsigned short Pb[64 * 72];   // P bf16 [q][key]
    __shared__ float row_m[64], row_l[64];
    __shared__ float mem_mm[64], mem_alpha[64], mem_suml[64];

    // Q fragments in registers (constant across the K loop)
    bf16x8 qreg[2];
#pragma unroll
    for (int kst = 0; kst < 2; kst++)
        qreg[kst] = *(const bf16x8*)(qkv4 + (size_t)(q0 + w * 16 + lrow) * 4096
                                     + h * HD + kst * 32 + lk);

    // K/V prefetch registers
    bf16x8 kr[2];
    ushort8 va, vb;
    const int vpr = t & 31, veg = t >> 5;

    float m_i[4], l_i[4];
    floatx4 Oacc[4];
#pragma unroll
    for (int r = 0; r < 4; r++) { m_i[r] = -1e30f; l_i[r] = 0.f; }
#pragma unroll
    for (int et = 0; et < 4; et++) Oacc[et] = (floatx4)0.f;

    const int krow = (t >> 3);          // rows 0..31 for p=0, +32 for p=1
    const int kcol = (t & 7) * 8;

    // prologue: stage tile 'lo'
    if (lo < hi) {
        const int j0 = lo * 64;
#pragma unroll
        for (int p = 0; p < 2; p++)
            kr[p] = *(const bf16x8*)(qkv4 + (size_t)(j0 + p * 32 + krow) * 4096
                                     + D + h * HD + kcol);
        const unsigned short* v0 =
            qkv4 + (size_t)(j0 + 2 * vpr) * 4096 + 2 * D + h * HD + veg * 8;
        va = *(const ushort8*)v0;
        vb = *(const ushort8*)(v0 + 4096);
#pragma unroll
        for (int p = 0; p < 2; p++)
            *(bf16x8*)&Ks[(p * 32 + krow) * 72 + kcol] = kr[p];
#pragma unroll
        for (int j = 0; j < 8; j++) {
            unsigned int pk = (unsigned int)va[j] | ((unsigned int)vb[j] << 16);
            *(unsigned int*)&Vt[(veg * 8 + j) * 72 + 2 * vpr] = pk;
        }
        __syncthreads();
    }

    for (int jt = lo; jt < hi; jt++) {
        const int j0 = jt * 64;
        const bool pf = (jt + 1 < hi);
        if (pf) {
            const int j0n = (jt + 1) * 64;
#pragma unroll
            for (int p = 0; p < 2; p++)
                kr[p] = *(const bf16x8*)(qkv4 + (size_t)(j0n + p * 32 + krow) * 4096
                                         + D + h * HD + kcol);
            const unsigned short* v0 =
                qkv4 + (size_t)(j0n + 2 * vpr) * 4096 + 2 * D + h * HD + veg * 8;
            va = *(const ushort8*)v0;
            vb = *(const ushort8*)(v0 + 4096);
        }

        // S = Q K^T
        floatx4 S[4];
#pragma unroll
        for (int nt = 0; nt < 4; nt++) S[nt] = (floatx4)0.f;
        __builtin_amdgcn_s_setprio(1);
#pragma unroll
        for (int kst = 0; kst < 2; kst++) {
#pragma unroll
            for (int nt = 0; nt < 4; nt++) {
                bf16x8 bk = *(const bf16x8*)&Ks[(nt * 16 + lrow) * 72 + kst * 32 + lk];
                S[nt] = __builtin_amdgcn_mfma_f32_16x16x32_bf16(qreg[kst], bk, S[nt], 0, 0, 0);
            }
        }
        __builtin_amdgcn_s_setprio(0);

        // online softmax; P -> Pb (bf16). Pb rows are wave-local: no barrier.
#pragma unroll
        for (int r = 0; r < 4; r++) {
            const int qg = q0 + w * 16 + rrow + r;
            float sc[4];
            float mx = -1e30f;
#pragma unroll
            for (int nt = 0; nt < 4; nt++) {
                sc[nt] = S[nt][r] * SCALE;
                if (j0 + nt * 16 + lrow > qg) sc[nt] = -1e30f;
                mx = fmaxf(mx, sc[nt]);
            }
#pragma unroll
            for (int off = 1; off < 16; off <<= 1)
                mx = fmaxf(mx, __shfl_xor(mx, off));
            if (mx <= -1e29f) {
                // entire tile masked for this row (later-split early rows)
#pragma unroll
                for (int nt = 0; nt < 4; nt++)
                    Pb[(w * 16 + rrow + r) * 72 + nt * 16 + lrow] = 0;
                continue;
            }
            const float newm  = fmaxf(m_i[r], mx);
            const float alpha = __expf(m_i[r] - newm);
            m_i[r] = newm;
            float ps = 0.f;
#pragma unroll
            for (int nt = 0; nt < 4; nt++) {
                float pe = __expf(sc[nt] - newm);
                ps += pe;
                Pb[(w * 16 + rrow + r) * 72 + nt * 16 + lrow] = f32_to_bf16(pe);
            }
#pragma unroll
            for (int off = 1; off < 16; off <<= 1)
                ps += __shfl_xor(ps, off);
            l_i[r] = l_i[r] * alpha + ps;
#pragma unroll
            for (int et = 0; et < 4; et++) Oacc[et][r] *= alpha;
        }

        // O += P @ V   (Pb rows read back by the wave that wrote them)
        __builtin_amdgcn_s_setprio(1);
#pragma unroll
        for (int kst = 0; kst < 2; kst++) {
            bf16x8 ap = *(const bf16x8*)&Pb[(w * 16 + lrow) * 72 + kst * 32 + lk];
#pragma unroll
            for (int et = 0; et < 4; et++) {
                bf16x8 bv = *(const bf16x8*)&Vt[(et * 16 + lrow) * 72 + kst * 32 + lk];
                Oacc[et] = __builtin_amdgcn_mfma_f32_16x16x32_bf16(ap, bv, Oacc[et], 0, 0, 0);
            }
        }
        __builtin_amdgcn_s_setprio(0);

        if (pf) {
            __syncthreads();            // all waves done reading Ks/Vt
#pragma unroll
            for (int p = 0; p < 2; p++)
                *(bf16x8*)&Ks[(p * 32 + krow) * 72 + kcol] = kr[p];
#pragma unroll
            for (int j = 0; j < 8; j++) {
                unsigned int pk = (unsigned int)va[j] | ((unsigned int)vb[j] << 16);
                *(unsigned int*)&Vt[(veg * 8 + j) * 72 + 2 * vpr] = pk;
            }
            __syncthreads();            // staging visible
        }
    }

    if (s != 0) {
        // write partials straight from registers
#pragma unroll
        for (int r = 0; r < 4; r++) {
            const int ql = w * 16 + rrow + r;
            if (lrow == 0) mlpart[(size_t)part * 64 + ql] = make_float2(m_i[r], l_i[r]);
#pragma unroll
            for (int et = 0; et < 4; et++)
                Opart[((size_t)part * 64 + ql) * 64 + et * 16 + lrow] = Oacc[et][r];
        }
        return;
    }

    // ---- split 0: fold precomputed memory-key scores, then write partials ----
#pragma unroll
    for (int r = 0; r < 4; r++) {
        const int ql = w * 16 + rrow + r;
        if (lrow == 0) { row_m[ql] = m_i[r]; row_l[ql] = l_i[r]; }
    }
    __syncthreads();

    if (t < 64) {
        const int qi = t, qg = q0 + qi;
        const float* msp = mem_scores + ((size_t)qg * H + h) * LL;
        float ms[LL];
#pragma unroll
        for (int l = 0; l < LL; l++) ms[l] = msp[l];    // already scaled
        const float mo = row_m[qi];
        float mm = mo;
#pragma unroll
        for (int l = 0; l < LL; l++) mm = fmaxf(mm, ms[l]);
        const float alpha = __expf(mo - mm);
        float suml = 0.f;
        float* mp = memP + ((size_t)qg * H + h) * LL;
#pragma unroll
        for (int l = 0; l < LL; l++) {
            float pe = __expf(ms[l] - mm);
            suml += pe;
            mp[l] = pe;
        }
        mem_mm[qi] = mm; mem_alpha[qi] = alpha; mem_suml[qi] = suml;
    }
    __syncthreads();

#pragma unroll
    for (int r = 0; r < 4; r++) {
        const int ql = w * 16 + rrow + r;
        const float alpha = mem_alpha[ql];
        if (lrow == 0)
            mlpart[(size_t)part * 64 + ql] =
                make_float2(mem_mm[ql], l_i[r] * alpha + mem_suml[ql]);
#pragma unroll
        for (int et = 0; et < 4; et++)
            Opart[((size_t)part * 64 + ql) * 64 + et * 16 + lrow] = Oacc[et][r] * alpha;
    }
}

// ---------------------------------------------------------------------------
// merge: combine the four key-split partials per (h, qt), normalize.
// Writes token context (f32), final normalized mem weights mwf, and
// Pmem[s,h] = sum_l mwf (for the bv bias term).
// ---------------------------------------------------------------------------
__global__ __launch_bounds__(256) void attn_merge_kernel(
    const float* __restrict__ Opart, const float2* __restrict__ mlpart,
    const float* __restrict__ memP,
    float* __restrict__ tok, float* __restrict__ mwf, float* __restrict__ Pmem)
{
    const int blk = blockIdx.x;            // h*32 + qt
    const int h = blk >> 5, qt = blk & 31;
    const int q0 = qt * 64;
    const int t = threadIdx.x, tx = t & 15, ty = t >> 4;
    const size_t pb = (size_t)blk * 4;
#pragma unroll
    for (int i = 0; i < 4; i++) {
        const int qi = ty * 4 + i, qg = q0 + qi;
        float2 ml[4];
#pragma unroll
        for (int ps = 0; ps < 4; ps++) ml[ps] = mlpart[(pb + ps) * 64 + qi];
        float M = ml[0].x;
#pragma unroll
        for (int ps = 1; ps < 4; ps++) M = fmaxf(M, ml[ps].x);
        float f[4], L = 0.f;
#pragma unroll
        for (int ps = 0; ps < 4; ps++) { f[ps] = __expf(ml[ps].x - M); L += ml[ps].y * f[ps]; }
        const float rl = 1.f / L;
        float4 o = make_float4(0.f, 0.f, 0.f, 0.f);
#pragma unroll
        for (int ps = 0; ps < 4; ps++) {
            const float fs = f[ps] * rl;
            float4 op = *(const float4*)&Opart[((pb + ps) * 64 + qi) * 64 + tx * 4];
            o.x += op.x * fs; o.y += op.y * fs; o.z += op.z * fs; o.w += op.w * fs;
        }
        *(float4*)&tok[(size_t)qg * D + h * HD + tx * 4] = o;
        if (tx == 0) {
            const float w0 = f[0] * rl;    // memP carried split-0's running max
            const float* mp = memP + ((size_t)qg * H + h) * LL;
            float* mw = mwf + ((size_t)qg * H + h) * LL;
            float psum = 0.f;
#pragma unroll
            for (int l = 0; l < LL; l++) { float v = mp[l] * w0; mw[l] = v; psum += v; }
            Pmem[(size_t)qg * H + h] = psum;
        }
    }
}

// ---------------------------------------------------------------------------
// rbar[h,s,:] = sum_l mwf[s,h,l] * ri[s*8+l,:]   (bf16 out). grid = 2048 (s).
// ---------------------------------------------------------------------------
__global__ __launch_bounds__(256) void rbar_kernel(
    const float* __restrict__ mwf, const unsigned short* __restrict__ ri,
    unsigned short* __restrict__ rbar)
{
    const int s = blockIdx.x, t = threadIdx.x;
    __shared__ unsigned short riS[LL * D];
    __shared__ float wS[H * LL];
    {
        const unsigned short* src = ri + (size_t)s * (LL * D);
#pragma unroll
        for (int j = 0; j < 4; j++) {
            const int off = (j * 256 + t) * 8;
            *(ushort8*)&riS[off] = *(const ushort8*)(src + off);
        }
    }
    if (t < H * LL) wS[t] = mwf[(size_t)s * (H * LL) + t];
    __syncthreads();
    const int c4 = t * 4;
#pragma unroll
    for (int hh = 0; hh < H; hh++) {
        float v0 = 0.f, v1 = 0.f, v2 = 0.f, v3 = 0.f;
#pragma unroll
        for (int l = 0; l < LL; l++) {
            const float wv = wS[hh * LL + l];
            ushort4 rr = *(const ushort4*)&riS[l * D + c4];
            v0 += wv * bf2f(rr.x); v1 += wv * bf2f(rr.y);
            v2 += wv * bf2f(rr.z); v3 += wv * bf2f(rr.w);
        }
        ushort4 o;
        o.x = f32_to_bf16(v0); o.y = f32_to_bf16(v1);
        o.z = f32_to_bf16(v2); o.w = f32_to_bf16(v3);
        *(ushort4*)(rbar + ((size_t)hh * SEQ + s) * D + c4) = o;
    }
}

// ---------------------------------------------------------------------------
// ctx GEMM: ctx[s, h*64+e] = bf16( rbar[h,s,:] . Wv[h*64+e,:]
//                                  + bv[h*64+e]*Pmem[s,h] + tok[s,h*64+e] )
// 128(M)x64(N) tile, BK=32, 4 waves (wave = m-subtile). grid = (16 mt, 16 h).
// ---------------------------------------------------------------------------
__global__ __launch_bounds__(256) void gemm_ctx_kernel(
    const unsigned short* __restrict__ rbar, const unsigned short* __restrict__ W4,
    const float* __restrict__ bqkv, const float* __restrict__ Pmem,
    const float* __restrict__ tok, unsigned short* __restrict__ ctx)
{
    const int mt = blockIdx.x;      // 0..15
    const int h  = blockIdx.y;      // 0..15
    const unsigned short* A  = rbar + (size_t)h * SEQ * D + (size_t)mt * 128 * D;
    const unsigned short* Wv = W4 + (size_t)(2 * D + h * HD) * D;   // 64 rows x 1024
    const float* bv = bqkv + 2 * D + h * HD;

    __shared__ unsigned short As[128 * 32];
    __shared__ unsigned short Ws[64 * 32];
    const int t    = threadIdx.x;
    const int wave = t >> 6, lane = t & 63;

    floatx4 acc[2][4];
#pragma unroll
    for (int i = 0; i < 2; i++)
#pragma unroll
        for (int j = 0; j < 4; j++) acc[i][j] = (floatx4)0.f;

    const int lrow = lane >> 2;
    const int lcol = (lane & 3) * 8;
    const unsigned short* Ag = A  + (size_t)(wave * 32 + lrow) * D + lcol;
    const unsigned short* Wg = Wv + (size_t)(wave * 32 + lrow) * D + lcol;  // waves 0,1 only
    unsigned short* Asw = &As[wave * 32 * 32];
    unsigned short* Wsw = &Ws[wave * 32 * 32];
    const size_t rowskip = (size_t)16 * D;

    const int arow  = lane & 15;
    const int aquad = (lane >> 4) * 8;

    for (int k0 = 0; k0 < D; k0 += 32) {
        load_lds16(Ag + k0,           Asw);
        load_lds16(Ag + k0 + rowskip, Asw + 16 * 32);
        if (wave < 2) {
            load_lds16(Wg + k0,           Wsw);
            load_lds16(Wg + k0 + rowskip, Wsw + 16 * 32);
        }
        __syncthreads();

        bf16x8 af[2], wf[4];
#pragma unroll
        for (int mi = 0; mi < 2; mi++)
            af[mi] = *(const bf16x8*)&As[(wave * 32 + mi * 16 + arow) * 32 + aquad];
#pragma unroll
        for (int ni = 0; ni < 4; ni++)
            wf[ni] = *(const bf16x8*)&Ws[(ni * 16 + arow) * 32 + aquad];
#pragma unroll
        for (int mi = 0; mi < 2; mi++)
#pragma unroll
            for (int ni = 0; ni < 4; ni++)
                acc[mi][ni] = __builtin_amdgcn_mfma_f32_16x16x32_bf16(
                    af[mi], wf[ni], acc[mi][ni], 0, 0, 0);
        __syncthreads();
    }

    const int crow = (lane >> 4) * 4, ccol = lane & 15;
#pragma unroll
    for (int mi = 0; mi < 2; mi++) {
#pragma unroll
        for (int ni = 0; ni < 4; ni++) {
            const int e  = ni * 16 + ccol;
            const float bb = bv[e];
#pragma unroll
            for (int r = 0; r < 4; r++) {
                const int grow = mt * 128 + wave * 32 + mi * 16 + crow + r;
                float v = acc[mi][ni][r] + bb * Pmem[(size_t)grow * H + h]
                          + tok[(size_t)grow * D + h * HD + e];
                ctx[(size_t)grow * D + h * HD + e] = f32_to_bf16(v);
            }
        }
    }
}

// ---------------------------------------------------------------------------
extern "C" void kernel_launch(void* const* d_in, const int* in_sizes, int n_in,
                              void* d_out, int out_size, void* d_ws, size_t ws_size,
                              hipStream_t stream)
{
    const float* x    = (const float*)d_in[0];
    const float* pv   = (const float*)d_in[1];
    const float* Wqkv = (const float*)d_in[2];
    const float* bqkv = (const float*)d_in[3];
    const float* Wcol = (const float*)d_in[4];
    const float* bcol = (const float*)d_in[5];
    const float* Wout = (const float*)d_in[6];
    const float* bout = (const float*)d_in[7];
    float* out = (float*)d_out;

    char* p = (char*)d_ws;
    unsigned short* x_bf    = (unsigned short*)p; p += (size_t)2048 * 1024 * 2;
    unsigned short* W4_bf   = (unsigned short*)p; p += (size_t)4096 * 1024 * 2;   // Wqkv | Wcol
    unsigned short* Wout_bf = (unsigned short*)p; p += (size_t)1024 * 1024 * 2;
    float*          b4      = (float*)p;          p += (size_t)4096 * 4;
    unsigned short* ri_bf   = (unsigned short*)p; p += (size_t)16384 * 1024 * 2;
    unsigned short* qkv4_bf = (unsigned short*)p; p += (size_t)2048 * 4096 * 2;   // Q|K|V|Qcol
    unsigned short* WkT_bf  = (unsigned short*)p; p += (size_t)16 * 1024 * 64 * 2;
    float*          scores  = (float*)p;          p += (size_t)2048 * 16 * 8 * 4;
    float*          memP    = (float*)p;          p += (size_t)2048 * 16 * 8 * 4;
    float*          mwf     = (float*)p;          p += (size_t)2048 * 16 * 8 * 4;
    float*          Pmem    = (float*)p;          p += (size_t)2048 * 16 * 4;
    float*          tok     = (float*)p;          p += (size_t)2048 * 1024 * 4;
    unsigned short* ctx_bf  = (unsigned short*)p; p += (size_t)2048 * 1024 * 2;
    float*          Opart   = (float*)p;          p += (size_t)2048 * 64 * 64 * 4;
    float2*         mlpart  = (float2*)p;         p += (size_t)2048 * 64 * 8;
    // U and rbar have disjoint lifetimes (U dead after memsc) -> share buffer
    unsigned short* Urb     = (unsigned short*)p; p += (size_t)16 * 2048 * 1024 * 2;
    // ~178 MB total

    // LN + all bf16 casts + bias concat
    prep_kernel<<<PREP_GRID, 256, 0, stream>>>(pv, x, Wqkv, Wcol, Wout, bqkv, bcol,
                                               ri_bf, x_bf, W4_bf, Wout_bf, b4);
    // per-head transposed Wk for the U GEMM
    wkt_kernel<<<256, 256, 0, stream>>>(Wqkv, WkT_bf);
    // qkv4 = x @ [Wqkv|Wcol]^T + [bqkv|bcol]   (fused, N=4096)
    gemm_bf16_kernel<unsigned short, true><<<dim3(32, 16, 1), 256, 0, stream>>>(
        x_bf, W4_bf, b4, qkv4_bf, 1024, 4096, 1024, 1024, 4096, 0, 0, 0);
    // U[h] = Qcol[h] @ Wk[h]   (K=64 head-batched; replaces the rk GEMM)
    gemm_bf16_kernel<unsigned short, false><<<dim3(8, 16, 16), 256, 0, stream>>>(
        qkv4_bf + 3 * D, WkT_bf, nullptr, Urb, 64, 1024, 4096, 64, 1024,
        (size_t)HD, (size_t)D * HD, (size_t)SEQ * D);
    // mem_scores = (U . ri + qcol.bk) * scale
    memsc_kernel<<<2048, 256, 0, stream>>>(Urb, ri_bf, qkv4_bf, bqkv, scores);
    // attention split (4-way) + merge
    attn_split_kernel<<<2048, 256, 0, stream>>>(qkv4_bf, scores, memP, Opart, mlpart);
    attn_merge_kernel<<<512, 256, 0, stream>>>(Opart, mlpart, memP, tok, mwf, Pmem);
    // rbar = sum_l mwf * ri   (reuses U's buffer)
    rbar_kernel<<<2048, 256, 0, stream>>>(mwf, ri_bf, Urb);
    // ctx = tok + Wv[h] @ rbar[h] + bv*Pmem   (replaces the rv GEMM + fold)
    gemm_ctx_kernel<<<dim3(16, 16), 256, 0, stream>>>(Urb, W4_bf, bqkv, Pmem, tok, ctx_bf);
    // out = ctx @ Wout^T + bout
    gemm_bf16_kernel<float, true><<<dim3(8, 16, 1), 256, 0, stream>>>(
        ctx_bf, Wout_bf, bout, out, 1024, 1024, 1024, 1024, 1024, 0, 0, 0);
}

// Round 3
// 339.107 us; speedup vs baseline: 1.0778x; 1.0137x over previous
//
#include <hip/hip_runtime.h>
#include <math.h>

#define D   1024
#define H   16
#define HD  64
#define SEQ 2048
#define LL  8
#define SCALE 0.125f

typedef __attribute__((ext_vector_type(8))) __bf16 bf16x8;
typedef __attribute__((ext_vector_type(4))) float floatx4;
typedef __attribute__((ext_vector_type(8))) unsigned short ushort8;

__device__ inline unsigned short f32_to_bf16(float f) {
    unsigned int u = __builtin_bit_cast(unsigned int, f);
    u += 0x7FFF + ((u >> 16) & 1);   // round-to-nearest-even
    return (unsigned short)(u >> 16);
}
__device__ inline float bf2f(unsigned short u) {
    unsigned int x = (unsigned int)u << 16;
    return __builtin_bit_cast(float, x);
}
__device__ inline void load_lds16(const void* g, void* l) {
    __builtin_amdgcn_global_load_lds(
        (__attribute__((address_space(1))) void*)g,
        (__attribute__((address_space(3))) void*)l, 16, 0, 0);
}

// XCD-aware swizzle: contiguous grid chunk per XCD -> A-panel L2 reuse.
__device__ inline void xcd_swizzle(int& bx, int& by) {
    const int gx   = gridDim.x;
    const int lin  = blockIdx.y * gx + blockIdx.x;
    const int nblk = gx * gridDim.y;
    const int virt = (lin & 7) * (nblk >> 3) + (lin >> 3);
    bx = virt % gx;
    by = virt / gx;
}

// ---------------------------------------------------------------------------
// prep: LN(reproject(pv)) -> ri_bf  |  f32->bf16 of x, Wqkv|Wcol (->W4), Wout
//       |  bias concat b4 = [bqkv, bcol]
// ---------------------------------------------------------------------------
#define NQ_X    524288
#define NQ_WQKV 786432
#define NQ_WC   262144
#define NQ_WO   262144
#define LN_BLK  16384
#define CVT_BLK 7168          // (NQ_X+NQ_WQKV+NQ_WC+NQ_WO)/256
#define PREP_GRID (LN_BLK + CVT_BLK + 4)

__global__ __launch_bounds__(256) void prep_kernel(
    const float* __restrict__ pv, const float* __restrict__ x,
    const float* __restrict__ Wqkv, const float* __restrict__ Wcol,
    const float* __restrict__ Wout, const float* __restrict__ bqkv,
    const float* __restrict__ bcol,
    unsigned short* __restrict__ ri, unsigned short* __restrict__ xb,
    unsigned short* __restrict__ W4b, unsigned short* __restrict__ Woutb,
    float* __restrict__ b4)
{
    const int b = blockIdx.x;
    const int t = threadIdx.x;
    if (b < LN_BLK) {
        // LayerNorm row r = s*L + l over d=1024
        const int r = b;
        const int s = r >> 3, l = r & 7;
        const int h = t >> 4, e = (t & 15) * 4;
        const size_t src = (size_t)l * (H * SEQ * HD) + (size_t)h * (SEQ * HD)
                         + (size_t)s * HD + e;
        float4 v = *(const float4*)(pv + src);
        float sum = v.x + v.y + v.z + v.w;
        float sq  = v.x * v.x + v.y * v.y + v.z * v.z + v.w * v.w;
#pragma unroll
        for (int off = 32; off; off >>= 1) {
            sum += __shfl_xor(sum, off);
            sq  += __shfl_xor(sq, off);
        }
        __shared__ float red[8];
        if ((t & 63) == 0) { red[(t >> 6) * 2] = sum; red[(t >> 6) * 2 + 1] = sq; }
        __syncthreads();
        sum = red[0] + red[2] + red[4] + red[6];
        sq  = red[1] + red[3] + red[5] + red[7];
        const float mean = sum * (1.f / 1024.f);
        const float var  = sq * (1.f / 1024.f) - mean * mean;
        const float rstd = rsqrtf(var + 1e-5f);
        ushort4 o;
        o.x = f32_to_bf16((v.x - mean) * rstd);
        o.y = f32_to_bf16((v.y - mean) * rstd);
        o.z = f32_to_bf16((v.z - mean) * rstd);
        o.w = f32_to_bf16((v.w - mean) * rstd);
        *(ushort4*)(ri + (size_t)r * D + t * 4) = o;
    } else if (b < LN_BLK + CVT_BLK) {
        const int i = (b - LN_BLK) * 256 + t;
        const float* src; unsigned short* dst; int off;
        if (i < NQ_X)                        { src = x;    dst = xb;    off = i; }
        else if (i < NQ_X + NQ_WQKV)         { src = Wqkv; dst = W4b;   off = i - NQ_X; }
        else if (i < NQ_X + NQ_WQKV + NQ_WC) {
            float4 v = ((const float4*)Wcol)[i - NQ_X - NQ_WQKV];
            ushort4 o;
            o.x = f32_to_bf16(v.x); o.y = f32_to_bf16(v.y);
            o.z = f32_to_bf16(v.z); o.w = f32_to_bf16(v.w);
            ((ushort4*)(W4b))[NQ_WQKV + (i - NQ_X - NQ_WQKV)] = o;
            return;
        }
        else                                 { src = Wout; dst = Woutb; off = i - NQ_X - NQ_WQKV - NQ_WC; }
        float4 v = ((const float4*)src)[off];
        ushort4 o;
        o.x = f32_to_bf16(v.x); o.y = f32_to_bf16(v.y);
        o.z = f32_to_bf16(v.z); o.w = f32_to_bf16(v.w);
        ((ushort4*)dst)[off] = o;
    } else {
        // bias concat: 1024 float4 quads, first 768 from bqkv, rest from bcol
        const int q = (b - LN_BLK - CVT_BLK) * 256 + t;
        float4 v = (q < 768) ? ((const float4*)bqkv)[q] : ((const float4*)bcol)[q - 768];
        ((float4*)b4)[q] = v;
    }
}

// ---------------------------------------------------------------------------
// wkt: WkT[h][c][e] = Wqkv[1024 + h*64 + e][c]  (bf16). Grid 256 = 16h x 16ct.
// ---------------------------------------------------------------------------
__global__ __launch_bounds__(256) void wkt_kernel(
    const float* __restrict__ Wqkv, unsigned short* __restrict__ WkT)
{
    const int h = blockIdx.x >> 4, ct = blockIdx.x & 15;
    const int c0 = ct * 64;
    const int t = threadIdx.x;
    __shared__ float tile[64][68];
    {
        const int e  = t >> 2;            // 0..63
        const int c4 = (t & 3) * 16;      // 0,16,32,48
        const float* src = Wqkv + (size_t)(D + h * HD + e) * D + c0 + c4;
#pragma unroll
        for (int j = 0; j < 4; j++) {
            float4 v = ((const float4*)src)[j];
            *(float4*)&tile[e][c4 + j * 4] = v;
        }
    }
    __syncthreads();
    {
        const int c  = t >> 2;            // local col 0..63
        const int e0 = (t & 3) * 16;      // 0,16,32,48
        ushort8 o0, o1;
#pragma unroll
        for (int j = 0; j < 8; j++) o0[j] = f32_to_bf16(tile[e0 + j][c]);
#pragma unroll
        for (int j = 0; j < 8; j++) o1[j] = f32_to_bf16(tile[e0 + 8 + j][c]);
        unsigned short* dst = WkT + (size_t)h * (D * HD) + (size_t)(c0 + c) * HD + e0;
        *(ushort8*)dst       = o0;
        *(ushort8*)(dst + 8) = o1;
    }
}

// ---------------------------------------------------------------------------
// bf16 MFMA GEMM: C[M,N] = A[M,K] @ W[N,K]^T (+ bias[N]). CT = float or ushort.
// 128x128 tile, BK=32, 4 waves, 4x4 16x16x32 MFMAs per wave. XCD-swizzled.
// Generalized: lda/ldw/ldc row strides, blockIdx.z batching via element strides.
// ---------------------------------------------------------------------------
template <typename CT, bool HAS_BIAS>
__global__ __launch_bounds__(256) void gemm_bf16_kernel(
    const unsigned short* __restrict__ A, const unsigned short* __restrict__ W,
    const float* __restrict__ bias, CT* __restrict__ C,
    int K, int N, int lda, int ldw, int ldc,
    size_t zsA, size_t zsW, size_t zsC)
{
    A += (size_t)blockIdx.z * zsA;
    W += (size_t)blockIdx.z * zsW;
    C += (size_t)blockIdx.z * zsC;

    __shared__ unsigned short As[128 * 32];
    __shared__ unsigned short Ws[128 * 32];
    const int t    = threadIdx.x;
    const int wave = t >> 6, lane = t & 63;
    const int wm   = wave >> 1, wn = wave & 1;
    int bx, by;
    xcd_swizzle(bx, by);
    const int m0 = by * 128, n0 = bx * 128;

    floatx4 acc[4][4];
#pragma unroll
    for (int i = 0; i < 4; i++)
#pragma unroll
        for (int j = 0; j < 4; j++) acc[i][j] = (floatx4)0.f;

    const int lrow = lane >> 2;
    const int lcol = (lane & 3) * 8;
    const unsigned short* Ag = A + (size_t)(m0 + wave * 32 + lrow) * lda + lcol;
    const unsigned short* Wg = W + (size_t)(n0 + wave * 32 + lrow) * ldw + lcol;
    unsigned short* Asw = &As[wave * 32 * 32];
    unsigned short* Wsw = &Ws[wave * 32 * 32];
    const size_t rowskipA = (size_t)16 * lda;
    const size_t rowskipW = (size_t)16 * ldw;

    const int arow  = lane & 15;
    const int aquad = (lane >> 4) * 8;

    for (int k0 = 0; k0 < K; k0 += 32) {
        load_lds16(Ag + k0,             Asw);
        load_lds16(Ag + k0 + rowskipA,  Asw + 16 * 32);
        load_lds16(Wg + k0,             Wsw);
        load_lds16(Wg + k0 + rowskipW,  Wsw + 16 * 32);
        __syncthreads();

        bf16x8 af[4], wf[4];
#pragma unroll
        for (int mi = 0; mi < 4; mi++)
            af[mi] = *(const bf16x8*)&As[(wm * 64 + mi * 16 + arow) * 32 + aquad];
#pragma unroll
        for (int ni = 0; ni < 4; ni++)
            wf[ni] = *(const bf16x8*)&Ws[(wn * 64 + ni * 16 + arow) * 32 + aquad];
#pragma unroll
        for (int mi = 0; mi < 4; mi++)
#pragma unroll
            for (int ni = 0; ni < 4; ni++)
                acc[mi][ni] = __builtin_amdgcn_mfma_f32_16x16x32_bf16(
                    af[mi], wf[ni], acc[mi][ni], 0, 0, 0);
        __syncthreads();
    }

    const int crow = (lane >> 4) * 4, ccol = lane & 15;
#pragma unroll
    for (int mi = 0; mi < 4; mi++) {
#pragma unroll
        for (int ni = 0; ni < 4; ni++) {
            const int gm = m0 + wm * 64 + mi * 16 + crow;
            const int gn = n0 + wn * 64 + ni * 16 + ccol;
            float bb = 0.f;
            if constexpr (HAS_BIAS) bb = bias[gn];
#pragma unroll
            for (int r = 0; r < 4; r++) {
                float v = acc[mi][ni][r] + bb;
                if constexpr (sizeof(CT) == 2)
                    C[(size_t)(gm + r) * ldc + gn] = (CT)f32_to_bf16(v);
                else
                    C[(size_t)(gm + r) * ldc + gn] = v;
            }
        }
    }
}

// ---------------------------------------------------------------------------
// memsc: mem_scores[s,h,l] = ( U[h,s,:].ri[s,l,:] + qcol[s,h,:].bk[h,:] )*SCALE
// grid = 2048 (one block per s).
// ---------------------------------------------------------------------------
#define RI_STRIDE 1032    // padded ushort row stride: spreads l over banks

__global__ __launch_bounds__(256) void memsc_kernel(
    const unsigned short* __restrict__ U, const unsigned short* __restrict__ ri,
    const unsigned short* __restrict__ qkv4, const float* __restrict__ bqkv,
    float* __restrict__ scores)
{
    const int s = blockIdx.x;
    const int t = threadIdx.x;
    __shared__ unsigned short riS[LL * RI_STRIDE];
    __shared__ float qbS[H];
    // stage ri[s] : 8 rows x 1024
    {
        const unsigned short* src = ri + (size_t)s * (LL * D);
#pragma unroll
        for (int j = 0; j < 4; j++) {
            const int off = (j * 256 + t) * 8;        // 0..8191
            const int l = off >> 10, c = off & 1023;
            ushort8 v = *(const ushort8*)(src + off);
            *(ushort8*)&riS[l * RI_STRIDE + c] = v;
        }
    }
    // qb[h] = qcol[s,h,:] . bk[h,:]
    {
        const int h = t >> 4, sub = t & 15;
        const unsigned short* qc = qkv4 + (size_t)s * 4096 + 3 * D + h * HD + sub * 4;
        const float* bk = bqkv + D + h * HD + sub * 4;
        float acc = 0.f;
#pragma unroll
        for (int j = 0; j < 4; j++) acc += bf2f(qc[j]) * bk[j];
#pragma unroll
        for (int off = 1; off < 16; off <<= 1) acc += __shfl_xor(acc, off);
        if (sub == 0) qbS[h] = acc;
    }
    __syncthreads();
    // 128 (h,l) pairs x 2 half-threads each, 512-wide dot per thread
    const int p = t >> 1, half = t & 1;
    const int h = p >> 3, l = p & 7;
    const unsigned short* Up = U + ((size_t)h * SEQ + s) * D + half * 512;
    const unsigned short* rp = &riS[l * RI_STRIDE + half * 512];
    float acc = 0.f;
#pragma unroll 4
    for (int j = 0; j < 64; j++) {
        ushort8 u = *(const ushort8*)(Up + j * 8);
        ushort8 r = *(const ushort8*)(rp + j * 8);
#pragma unroll
        for (int k = 0; k < 8; k++) acc += bf2f(u[k]) * bf2f(r[k]);
    }
    acc += __shfl_xor(acc, 1);
    if (half == 0)
        scores[((size_t)s * H + h) * LL + l] = (acc + qbS[h]) * SCALE;
}

// ---------------------------------------------------------------------------
// Split-K MFMA flash dual attention (token keys only), 4-way key split.
// Q in registers; K/V reg-prefetch (T14); 2 barriers per tile; setprio (T5).
// LPT dispatch: qt = 31 - g so the longest splits launch first (tail fill).
// Non-diagonal tiles skip causal masking; defer-max (T13) skips the rescale
// when the running max doesn't grow past THR=8.
// Split 0 folds the 8 precomputed memory-key scores and writes memP.
// ---------------------------------------------------------------------------
__global__ __launch_bounds__(256) void attn_split_kernel(
    const unsigned short* __restrict__ qkv4,
    const float* __restrict__ mem_scores, float* __restrict__ memP,
    float* __restrict__ Opart, float2* __restrict__ mlpart)
{
    const int t    = threadIdx.x;
    const int w    = t >> 6, lane = t & 63;
    const int lrow = lane & 15;
    const int lk   = (lane >> 4) * 8;
    const int rrow = (lane >> 4) * 4;
    const int lin  = blockIdx.x;
    const int hsp  = lin & 63, g = lin >> 6;
    const int h    = hsp >> 2, s = hsp & 3;
    const int qt   = 31 - g;               // LPT: longest first
    const int q0   = qt * 64;
    const int n    = qt + 1;
    const int lo   = (s * n) >> 2, hi = ((s + 1) * n) >> 2;
    const int part = (h * 32 + qt) * 4 + s;

    __shared__ unsigned short Ks[64 * 72];   // [key][e]
    __shared__ unsigned short Vt[64 * 72];   // [e][key]
    __shared__ unsigned short Pb[64 * 72];   // P bf16 [q][key]
    __shared__ float row_m[64], row_l[64];
    __shared__ float mem_mm[64], mem_alpha[64], mem_suml[64];

    // Q fragments in registers (constant across the K loop)
    bf16x8 qreg[2];
#pragma unroll
    for (int kst = 0; kst < 2; kst++)
        qreg[kst] = *(const bf16x8*)(qkv4 + (size_t)(q0 + w * 16 + lrow) * 4096
                                     + h * HD + kst * 32 + lk);

    // K/V prefetch registers
    bf16x8 kr[2];
    ushort8 va, vb;
    const int vpr = t & 31, veg = t >> 5;

    float m_i[4], l_i[4];
    floatx4 Oacc[4];
#pragma unroll
    for (int r = 0; r < 4; r++) { m_i[r] = -1e30f; l_i[r] = 0.f; }
#pragma unroll
    for (int et = 0; et < 4; et++) Oacc[et] = (floatx4)0.f;

    const int krow = (t >> 3);          // rows 0..31 for p=0, +32 for p=1
    const int kcol = (t & 7) * 8;

    // prologue: stage tile 'lo'
    if (lo < hi) {
        const int j0 = lo * 64;
#pragma unroll
        for (int p = 0; p < 2; p++)
            kr[p] = *(const bf16x8*)(qkv4 + (size_t)(j0 + p * 32 + krow) * 4096
                                     + D + h * HD + kcol);
        const unsigned short* v0 =
            qkv4 + (size_t)(j0 + 2 * vpr) * 4096 + 2 * D + h * HD + veg * 8;
        va = *(const ushort8*)v0;
        vb = *(const ushort8*)(v0 + 4096);
#pragma unroll
        for (int p = 0; p < 2; p++)
            *(bf16x8*)&Ks[(p * 32 + krow) * 72 + kcol] = kr[p];
#pragma unroll
        for (int j = 0; j < 8; j++) {
            unsigned int pk = (unsigned int)va[j] | ((unsigned int)vb[j] << 16);
            *(unsigned int*)&Vt[(veg * 8 + j) * 72 + 2 * vpr] = pk;
        }
        __syncthreads();
    }

    for (int jt = lo; jt < hi; jt++) {
        const int j0 = jt * 64;
        const bool pf = (jt + 1 < hi);
        if (pf) {
            const int j0n = (jt + 1) * 64;
#pragma unroll
            for (int p = 0; p < 2; p++)
                kr[p] = *(const bf16x8*)(qkv4 + (size_t)(j0n + p * 32 + krow) * 4096
                                         + D + h * HD + kcol);
            const unsigned short* v0 =
                qkv4 + (size_t)(j0n + 2 * vpr) * 4096 + 2 * D + h * HD + veg * 8;
            va = *(const ushort8*)v0;
            vb = *(const ushort8*)(v0 + 4096);
        }

        // S = Q K^T
        floatx4 S[4];
#pragma unroll
        for (int nt = 0; nt < 4; nt++) S[nt] = (floatx4)0.f;
        __builtin_amdgcn_s_setprio(1);
#pragma unroll
        for (int kst = 0; kst < 2; kst++) {
#pragma unroll
            for (int nt = 0; nt < 4; nt++) {
                bf16x8 bk = *(const bf16x8*)&Ks[(nt * 16 + lrow) * 72 + kst * 32 + lk];
                S[nt] = __builtin_amdgcn_mfma_f32_16x16x32_bf16(qreg[kst], bk, S[nt], 0, 0, 0);
            }
        }
        __builtin_amdgcn_s_setprio(0);

        // online softmax; P -> Pb (bf16). Pb rows are wave-local: no barrier.
        if (j0 != q0) {
            // fully-unmasked tile (jt < qt): no causal mask, defer-max (T13)
#pragma unroll
            for (int r = 0; r < 4; r++) {
                float sc[4];
#pragma unroll
                for (int nt = 0; nt < 4; nt++) sc[nt] = S[nt][r] * SCALE;
                float mx = fmaxf(fmaxf(sc[0], sc[1]), fmaxf(sc[2], sc[3]));
#pragma unroll
                for (int off = 1; off < 16; off <<= 1)
                    mx = fmaxf(mx, __shfl_xor(mx, off));
                const bool keep = __all(mx <= m_i[r] + 8.f);
                const float newm = keep ? m_i[r] : fmaxf(m_i[r], mx);
                float ps = 0.f;
#pragma unroll
                for (int nt = 0; nt < 4; nt++) {
                    float pe = __expf(sc[nt] - newm);
                    ps += pe;
                    Pb[(w * 16 + rrow + r) * 72 + nt * 16 + lrow] = f32_to_bf16(pe);
                }
#pragma unroll
                for (int off = 1; off < 16; off <<= 1)
                    ps += __shfl_xor(ps, off);
                if (keep) {
                    l_i[r] += ps;
                } else {
                    const float alpha = __expf(m_i[r] - newm);
                    m_i[r] = newm;
                    l_i[r] = l_i[r] * alpha + ps;
#pragma unroll
                    for (int et = 0; et < 4; et++) Oacc[et][r] *= alpha;
                }
            }
        } else {
            // diagonal tile: causal masking
#pragma unroll
            for (int r = 0; r < 4; r++) {
                const int qg = q0 + w * 16 + rrow + r;
                float sc[4];
                float mx = -1e30f;
#pragma unroll
                for (int nt = 0; nt < 4; nt++) {
                    sc[nt] = S[nt][r] * SCALE;
                    if (j0 + nt * 16 + lrow > qg) sc[nt] = -1e30f;
                    mx = fmaxf(mx, sc[nt]);
                }
#pragma unroll
                for (int off = 1; off < 16; off <<= 1)
                    mx = fmaxf(mx, __shfl_xor(mx, off));
                const float newm  = fmaxf(m_i[r], mx);
                const float alpha = __expf(m_i[r] - newm);
                m_i[r] = newm;
                float ps = 0.f;
#pragma unroll
                for (int nt = 0; nt < 4; nt++) {
                    float pe = __expf(sc[nt] - newm);
                    ps += pe;
                    Pb[(w * 16 + rrow + r) * 72 + nt * 16 + lrow] = f32_to_bf16(pe);
                }
#pragma unroll
                for (int off = 1; off < 16; off <<= 1)
                    ps += __shfl_xor(ps, off);
                l_i[r] = l_i[r] * alpha + ps;
#pragma unroll
                for (int et = 0; et < 4; et++) Oacc[et][r] *= alpha;
            }
        }

        // O += P @ V   (Pb rows read back by the wave that wrote them)
        __builtin_amdgcn_s_setprio(1);
#pragma unroll
        for (int kst = 0; kst < 2; kst++) {
            bf16x8 ap = *(const bf16x8*)&Pb[(w * 16 + lrow) * 72 + kst * 32 + lk];
#pragma unroll
            for (int et = 0; et < 4; et++) {
                bf16x8 bv = *(const bf16x8*)&Vt[(et * 16 + lrow) * 72 + kst * 32 + lk];
                Oacc[et] = __builtin_amdgcn_mfma_f32_16x16x32_bf16(ap, bv, Oacc[et], 0, 0, 0);
            }
        }
        __builtin_amdgcn_s_setprio(0);

        if (pf) {
            __syncthreads();            // all waves done reading Ks/Vt
#pragma unroll
            for (int p = 0; p < 2; p++)
                *(bf16x8*)&Ks[(p * 32 + krow) * 72 + kcol] = kr[p];
#pragma unroll
            for (int j = 0; j < 8; j++) {
                unsigned int pk = (unsigned int)va[j] | ((unsigned int)vb[j] << 16);
                *(unsigned int*)&Vt[(veg * 8 + j) * 72 + 2 * vpr] = pk;
            }
            __syncthreads();            // staging visible
        }
    }

    if (s != 0) {
        // write partials straight from registers
#pragma unroll
        for (int r = 0; r < 4; r++) {
            const int ql = w * 16 + rrow + r;
            if (lrow == 0) mlpart[(size_t)part * 64 + ql] = make_float2(m_i[r], l_i[r]);
#pragma unroll
            for (int et = 0; et < 4; et++)
                Opart[((size_t)part * 64 + ql) * 64 + et * 16 + lrow] = Oacc[et][r];
        }
        return;
    }

    // ---- split 0: fold precomputed memory-key scores, then write partials ----
#pragma unroll
    for (int r = 0; r < 4; r++) {
        const int ql = w * 16 + rrow + r;
        if (lrow == 0) { row_m[ql] = m_i[r]; row_l[ql] = l_i[r]; }
    }
    __syncthreads();

    if (t < 64) {
        const int qi = t, qg = q0 + qi;
        const float* msp = mem_scores + ((size_t)qg * H + h) * LL;
        float ms[LL];
#pragma unroll
        for (int l = 0; l < LL; l++) ms[l] = msp[l];    // already scaled
        const float mo = row_m[qi];
        float mm = mo;
#pragma unroll
        for (int l = 0; l < LL; l++) mm = fmaxf(mm, ms[l]);
        const float alpha = __expf(mo - mm);
        float suml = 0.f;
        float* mp = memP + ((size_t)qg * H + h) * LL;
#pragma unroll
        for (int l = 0; l < LL; l++) {
            float pe = __expf(ms[l] - mm);
            suml += pe;
            mp[l] = pe;
        }
        mem_mm[qi] = mm; mem_alpha[qi] = alpha; mem_suml[qi] = suml;
    }
    __syncthreads();

#pragma unroll
    for (int r = 0; r < 4; r++) {
        const int ql = w * 16 + rrow + r;
        const float alpha = mem_alpha[ql];
        if (lrow == 0)
            mlpart[(size_t)part * 64 + ql] =
                make_float2(mem_mm[ql], l_i[r] * alpha + mem_suml[ql]);
#pragma unroll
        for (int et = 0; et < 4; et++)
            Opart[((size_t)part * 64 + ql) * 64 + et * 16 + lrow] = Oacc[et][r] * alpha;
    }
}

// ---------------------------------------------------------------------------
// merge: combine the four key-split partials per (h, qt), normalize.
// Writes token context (f32), final normalized mem weights mwf, and
// Pmem[s,h] = sum_l mwf (for the bv bias term).
// ---------------------------------------------------------------------------
__global__ __launch_bounds__(256) void attn_merge_kernel(
    const float* __restrict__ Opart, const float2* __restrict__ mlpart,
    const float* __restrict__ memP,
    float* __restrict__ tok, float* __restrict__ mwf, float* __restrict__ Pmem)
{
    const int blk = blockIdx.x;            // h*32 + qt
    const int h = blk >> 5, qt = blk & 31;
    const int q0 = qt * 64;
    const int t = threadIdx.x, tx = t & 15, ty = t >> 4;
    const size_t pb = (size_t)blk * 4;
#pragma unroll
    for (int i = 0; i < 4; i++) {
        const int qi = ty * 4 + i, qg = q0 + qi;
        float2 ml[4];
#pragma unroll
        for (int ps = 0; ps < 4; ps++) ml[ps] = mlpart[(pb + ps) * 64 + qi];
        float M = ml[0].x;
#pragma unroll
        for (int ps = 1; ps < 4; ps++) M = fmaxf(M, ml[ps].x);
        float f[4], L = 0.f;
#pragma unroll
        for (int ps = 0; ps < 4; ps++) { f[ps] = __expf(ml[ps].x - M); L += ml[ps].y * f[ps]; }
        const float rl = 1.f / L;
        float4 o = make_float4(0.f, 0.f, 0.f, 0.f);
#pragma unroll
        for (int ps = 0; ps < 4; ps++) {
            const float fs = f[ps] * rl;
            float4 op = *(const float4*)&Opart[((pb + ps) * 64 + qi) * 64 + tx * 4];
            o.x += op.x * fs; o.y += op.y * fs; o.z += op.z * fs; o.w += op.w * fs;
        }
        *(float4*)&tok[(size_t)qg * D + h * HD + tx * 4] = o;
        if (tx == 0) {
            const float w0 = f[0] * rl;    // memP carried split-0's running max
            const float* mp = memP + ((size_t)qg * H + h) * LL;
            float* mw = mwf + ((size_t)qg * H + h) * LL;
            float psum = 0.f;
#pragma unroll
            for (int l = 0; l < LL; l++) { float v = mp[l] * w0; mw[l] = v; psum += v; }
            Pmem[(size_t)qg * H + h] = psum;
        }
    }
}

// ---------------------------------------------------------------------------
// rbar[h,s,:] = sum_l mwf[s,h,l] * ri[s*8+l,:]   (bf16 out). grid = 2048 (s).
// ---------------------------------------------------------------------------
__global__ __launch_bounds__(256) void rbar_kernel(
    const float* __restrict__ mwf, const unsigned short* __restrict__ ri,
    unsigned short* __restrict__ rbar)
{
    const int s = blockIdx.x, t = threadIdx.x;
    __shared__ unsigned short riS[LL * D];
    __shared__ float wS[H * LL];
    {
        const unsigned short* src = ri + (size_t)s * (LL * D);
#pragma unroll
        for (int j = 0; j < 4; j++) {
            const int off = (j * 256 + t) * 8;
            *(ushort8*)&riS[off] = *(const ushort8*)(src + off);
        }
    }
    if (t < H * LL) wS[t] = mwf[(size_t)s * (H * LL) + t];
    __syncthreads();
    const int c4 = t * 4;
#pragma unroll
    for (int hh = 0; hh < H; hh++) {
        float v0 = 0.f, v1 = 0.f, v2 = 0.f, v3 = 0.f;
#pragma unroll
        for (int l = 0; l < LL; l++) {
            const float wv = wS[hh * LL + l];
            ushort4 rr = *(const ushort4*)&riS[l * D + c4];
            v0 += wv * bf2f(rr.x); v1 += wv * bf2f(rr.y);
            v2 += wv * bf2f(rr.z); v3 += wv * bf2f(rr.w);
        }
        ushort4 o;
        o.x = f32_to_bf16(v0); o.y = f32_to_bf16(v1);
        o.z = f32_to_bf16(v2); o.w = f32_to_bf16(v3);
        *(ushort4*)(rbar + ((size_t)hh * SEQ + s) * D + c4) = o;
    }
}

// ---------------------------------------------------------------------------
// ctx GEMM: ctx[s, h*64+e] = bf16( rbar[h,s,:] . Wv[h*64+e,:]
//                                  + bv[h*64+e]*Pmem[s,h] + tok[s,h*64+e] )
// 128(M)x64(N) tile, BK=32, 4 waves (wave = m-subtile). grid = (16 mt, 16 h).
// ---------------------------------------------------------------------------
__global__ __launch_bounds__(256) void gemm_ctx_kernel(
    const unsigned short* __restrict__ rbar, const unsigned short* __restrict__ W4,
    const float* __restrict__ bqkv, const float* __restrict__ Pmem,
    const float* __restrict__ tok, unsigned short* __restrict__ ctx)
{
    const int mt = blockIdx.x;      // 0..15
    const int h  = blockIdx.y;      // 0..15
    const unsigned short* A  = rbar + (size_t)h * SEQ * D + (size_t)mt * 128 * D;
    const unsigned short* Wv = W4 + (size_t)(2 * D + h * HD) * D;   // 64 rows x 1024
    const float* bv = bqkv + 2 * D + h * HD;

    __shared__ unsigned short As[128 * 32];
    __shared__ unsigned short Ws[64 * 32];
    const int t    = threadIdx.x;
    const int wave = t >> 6, lane = t & 63;

    floatx4 acc[2][4];
#pragma unroll
    for (int i = 0; i < 2; i++)
#pragma unroll
        for (int j = 0; j < 4; j++) acc[i][j] = (floatx4)0.f;

    const int lrow = lane >> 2;
    const int lcol = (lane & 3) * 8;
    const unsigned short* Ag = A  + (size_t)(wave * 32 + lrow) * D + lcol;
    const unsigned short* Wg = Wv + (size_t)(wave * 32 + lrow) * D + lcol;  // waves 0,1 only
    unsigned short* Asw = &As[wave * 32 * 32];
    unsigned short* Wsw = &Ws[wave * 32 * 32];
    const size_t rowskip = (size_t)16 * D;

    const int arow  = lane & 15;
    const int aquad = (lane >> 4) * 8;

    for (int k0 = 0; k0 < D; k0 += 32) {
        load_lds16(Ag + k0,           Asw);
        load_lds16(Ag + k0 + rowskip, Asw + 16 * 32);
        if (wave < 2) {
            load_lds16(Wg + k0,           Wsw);
            load_lds16(Wg + k0 + rowskip, Wsw + 16 * 32);
        }
        __syncthreads();

        bf16x8 af[2], wf[4];
#pragma unroll
        for (int mi = 0; mi < 2; mi++)
            af[mi] = *(const bf16x8*)&As[(wave * 32 + mi * 16 + arow) * 32 + aquad];
#pragma unroll
        for (int ni = 0; ni < 4; ni++)
            wf[ni] = *(const bf16x8*)&Ws[(ni * 16 + arow) * 32 + aquad];
#pragma unroll
        for (int mi = 0; mi < 2; mi++)
#pragma unroll
            for (int ni = 0; ni < 4; ni++)
                acc[mi][ni] = __builtin_amdgcn_mfma_f32_16x16x32_bf16(
                    af[mi], wf[ni], acc[mi][ni], 0, 0, 0);
        __syncthreads();
    }

    const int crow = (lane >> 4) * 4, ccol = lane & 15;
#pragma unroll
    for (int mi = 0; mi < 2; mi++) {
#pragma unroll
        for (int ni = 0; ni < 4; ni++) {
            const int e  = ni * 16 + ccol;
            const float bb = bv[e];
#pragma unroll
            for (int r = 0; r < 4; r++) {
                const int grow = mt * 128 + wave * 32 + mi * 16 + crow + r;
                float v = acc[mi][ni][r] + bb * Pmem[(size_t)grow * H + h]
                          + tok[(size_t)grow * D + h * HD + e];
                ctx[(size_t)grow * D + h * HD + e] = f32_to_bf16(v);
            }
        }
    }
}

// ---------------------------------------------------------------------------
extern "C" void kernel_launch(void* const* d_in, const int* in_sizes, int n_in,
                              void* d_out, int out_size, void* d_ws, size_t ws_size,
                              hipStream_t stream)
{
    const float* x    = (const float*)d_in[0];
    const float* pv   = (const float*)d_in[1];
    const float* Wqkv = (const float*)d_in[2];
    const float* bqkv = (const float*)d_in[3];
    const float* Wcol = (const float*)d_in[4];
    const float* bcol = (const float*)d_in[5];
    const float* Wout = (const float*)d_in[6];
    const float* bout = (const float*)d_in[7];
    float* out = (float*)d_out;

    char* p = (char*)d_ws;
    unsigned short* x_bf    = (unsigned short*)p; p += (size_t)2048 * 1024 * 2;
    unsigned short* W4_bf   = (unsigned short*)p; p += (size_t)4096 * 1024 * 2;   // Wqkv | Wcol
    unsigned short* Wout_bf = (unsigned short*)p; p += (size_t)1024 * 1024 * 2;
    float*          b4      = (float*)p;          p += (size_t)4096 * 4;
    unsigned short* ri_bf   = (unsigned short*)p; p += (size_t)16384 * 1024 * 2;
    unsigned short* qkv4_bf = (unsigned short*)p; p += (size_t)2048 * 4096 * 2;   // Q|K|V|Qcol
    unsigned short* WkT_bf  = (unsigned short*)p; p += (size_t)16 * 1024 * 64 * 2;
    float*          scores  = (float*)p;          p += (size_t)2048 * 16 * 8 * 4;
    float*          memP    = (float*)p;          p += (size_t)2048 * 16 * 8 * 4;
    float*          mwf     = (float*)p;          p += (size_t)2048 * 16 * 8 * 4;
    float*          Pmem    = (float*)p;          p += (size_t)2048 * 16 * 4;
    float*          tok     = (float*)p;          p += (size_t)2048 * 1024 * 4;
    unsigned short* ctx_bf  = (unsigned short*)p; p += (size_t)2048 * 1024 * 2;
    float*          Opart   = (float*)p;          p += (size_t)2048 * 64 * 64 * 4;
    float2*         mlpart  = (float2*)p;         p += (size_t)2048 * 64 * 8;
    // U and rbar have disjoint lifetimes (U dead after memsc) -> share buffer
    unsigned short* Urb     = (unsigned short*)p; p += (size_t)16 * 2048 * 1024 * 2;
    // ~178 MB total

    // LN + all bf16 casts + bias concat
    prep_kernel<<<PREP_GRID, 256, 0, stream>>>(pv, x, Wqkv, Wcol, Wout, bqkv, bcol,
                                               ri_bf, x_bf, W4_bf, Wout_bf, b4);
    // per-head transposed Wk for the U GEMM
    wkt_kernel<<<256, 256, 0, stream>>>(Wqkv, WkT_bf);
    // qkv4 = x @ [Wqkv|Wcol]^T + [bqkv|bcol]   (fused, N=4096)
    gemm_bf16_kernel<unsigned short, true><<<dim3(32, 16, 1), 256, 0, stream>>>(
        x_bf, W4_bf, b4, qkv4_bf, 1024, 4096, 1024, 1024, 4096, 0, 0, 0);
    // U[h] = Qcol[h] @ Wk[h]   (K=64 head-batched; replaces the rk GEMM)
    gemm_bf16_kernel<unsigned short, false><<<dim3(8, 16, 16), 256, 0, stream>>>(
        qkv4_bf + 3 * D, WkT_bf, nullptr, Urb, 64, 1024, 4096, 64, 1024,
        (size_t)HD, (size_t)D * HD, (size_t)SEQ * D);
    // mem_scores = (U . ri + qcol.bk) * scale
    memsc_kernel<<<2048, 256, 0, stream>>>(Urb, ri_bf, qkv4_bf, bqkv, scores);
    // attention split (4-way, LPT-ordered) + merge
    attn_split_kernel<<<2048, 256, 0, stream>>>(qkv4_bf, scores, memP, Opart, mlpart);
    attn_merge_kernel<<<512, 256, 0, stream>>>(Opart, mlpart, memP, tok, mwf, Pmem);
    // rbar = sum_l mwf * ri   (reuses U's buffer)
    rbar_kernel<<<2048, 256, 0, stream>>>(mwf, ri_bf, Urb);
    // ctx = tok + Wv[h] @ rbar[h] + bv*Pmem   (replaces the rv GEMM + fold)
    gemm_ctx_kernel<<<dim3(16, 16), 256, 0, stream>>>(Urb, W4_bf, bqkv, Pmem, tok, ctx_bf);
    // out = ctx @ Wout^T + bout
    gemm_bf16_kernel<float, true><<<dim3(8, 16, 1), 256, 0, stream>>>(
        ctx_bf, Wout_bf, bout, out, 1024, 1024, 1024, 1024, 1024, 0, 0, 0);
}